// Round 4
// baseline (702.822 us; speedup 1.0000x reference)
//
#include <hip/hip_runtime.h>
#include <math.h>
#include <stdint.h>

#define BB 256
#define C_IN 7
#define TT 160
#define PATCH 10
#define D_MODEL 512
#define L_TOK 16
#define D_INNER 1024
#define D_STATE 16
#define DT_RANK 32
#define EPS 1e-5f
#define NROWS (BB*L_TOK)   // 4096
#define KPAD 96            // 70 padded to 3*32

typedef __bf16 bf16x8 __attribute__((ext_vector_type(8)));
typedef float  f32x4  __attribute__((ext_vector_type(4)));

__device__ __forceinline__ float siluf(float x){ return x / (1.f + __expf(-x)); }
__device__ __forceinline__ float softplusf(float x){ return (x > 20.f) ? x : log1pf(__expf(x)); }

__device__ __forceinline__ void gload_lds16(const void* gp, void* lp){
  __builtin_amdgcn_global_load_lds(
      (const __attribute__((address_space(1))) unsigned int*)(uintptr_t)gp,
      (__attribute__((address_space(3))) unsigned int*)(uintptr_t)lp, 16, 0, 0);
}

__device__ __forceinline__ float block_reduce_sum(float v, float* sred4){
  for(int off=32; off>0; off>>=1) v += __shfl_down(v, off, 64);
  int lane = threadIdx.x & 63, wid = threadIdx.x >> 6;
  if(lane==0) sred4[wid] = v;
  __syncthreads();
  if(threadIdx.x==0) sred4[0] = sred4[0]+sred4[1]+sred4[2]+sred4[3];
  __syncthreads();
  float r = sred4[0];
  __syncthreads();
  return r;
}

// ---------------------------------------------------------------------------
// transpose + fp32->bf16: in [z][K][N] f32 row-major -> out [z][N][K] bf16
// ---------------------------------------------------------------------------
__global__ __launch_bounds__(256) void transpose_bf16_kernel(
    const float* __restrict__ in, __bf16* __restrict__ out, int K, int N)
{
  __shared__ float tile[32][33];
  size_t moff = (size_t)blockIdx.z * K * N;
  int n0 = blockIdx.x*32, k0 = blockIdx.y*32;
  int tx = threadIdx.x, ty = threadIdx.y;
  #pragma unroll
  for(int rr=0;rr<4;rr++)
    tile[ty+rr*8][tx] = in[moff + (size_t)(k0+ty+rr*8)*N + n0+tx];
  __syncthreads();
  #pragma unroll
  for(int rr=0;rr<4;rr++)
    out[moff + (size_t)(n0+ty+rr*8)*K + k0+tx] = (__bf16)tile[tx][ty+rr*8];
}

// ---------------------------------------------------------------------------
// BN + patchify -> A[4096][96] bf16 (k>=70 zero-padded)
// ---------------------------------------------------------------------------
__global__ __launch_bounds__(256) void bn_patchify_kernel(
    const float* __restrict__ x, const float* __restrict__ bng,
    const float* __restrict__ bnb, const float* __restrict__ bnm,
    const float* __restrict__ bnv, __bf16* __restrict__ Abuf)
{
  int idx = blockIdx.x*256 + threadIdx.x;
  int row = idx / KPAD, k = idx % KPAD;
  int b = row >> 4, l = row & 15;
  float v = 0.f;
  if(k < C_IN*PATCH){
    int c = k / PATCH, j = k % PATCH;
    float xv = x[(b*C_IN + c)*TT + l*PATCH + j];
    v = (xv - bnm[c]) * rsqrtf(bnv[c] + EPS) * bng[c] + bnb[c];
  }
  Abuf[idx] = (__bf16)v;
}

__global__ __launch_bounds__(256) void cast_pad_pw_kernel(
    const float* __restrict__ pw, __bf16* __restrict__ pwb)
{
  int idx = blockIdx.x*256 + threadIdx.x;
  if(idx >= 512*KPAD) return;
  int n = idx / KPAD, k = idx % KPAD;
  pwb[idx] = (__bf16)(k < C_IN*PATCH ? pw[n*(C_IN*PATCH) + k] : 0.f);
}

// ---------------------------------------------------------------------------
// Generic MFMA bf16 GEMM: C[M,N](f32) (+)= A[M,K]@Bt[N,K]^T, strides lda/ldb.
// EPI: 0 = plain f32 store (ACC optional); 1 = dual store f32 C + bf16 Cb;
//      2 = C = softplus(acc + bias[n]).
// ---------------------------------------------------------------------------
template<int BN, int ACC, int EPI>
__global__ __launch_bounds__(256) void mfma_gemm(
    const __bf16* __restrict__ A, const __bf16* __restrict__ Bt,
    float* __restrict__ C, __bf16* __restrict__ Cb,
    const float* __restrict__ bias, int M, int N, int K, int lda, int ldb)
{
  constexpr int BM  = 128;
  constexpr int NGB = BN/16;
  constexpr int FN  = BN/32;
  constexpr int BPW = NGB/4;
  __shared__ __align__(16) __bf16 As[8*512];
  __shared__ __align__(16) __bf16 Bs[NGB*512];
  (void)M;
  int tid  = threadIdx.x;
  int lane = tid & 63, w = tid >> 6;
  int wrow = w >> 1, wcol = w & 1;
  int r = lane & 15, q = lane >> 4;
  int row0 = blockIdx.y*BM, col0 = blockIdx.x*BN;

  f32x4 acc[4][FN];
  #pragma unroll
  for(int i=0;i<4;i++)
    #pragma unroll
    for(int j=0;j<FN;j++) acc[i][j] = (f32x4)0.f;

  const __bf16* aSrc[2];
  #pragma unroll
  for(int g2=0;g2<2;g2++)
    aSrc[g2] = A + (size_t)(row0 + (w*2+g2)*16 + r)*lda + q*8;
  const __bf16* bSrc[BPW];
  #pragma unroll
  for(int g2=0;g2<BPW;g2++)
    bSrc[g2] = Bt + (size_t)(col0 + (w*BPW+g2)*16 + r)*ldb + q*8;

  for(int k0=0;k0<K;k0+=32){
    #pragma unroll
    for(int g2=0;g2<2;g2++)
      gload_lds16(aSrc[g2] + k0, As + (w*2+g2)*512);
    #pragma unroll
    for(int g2=0;g2<BPW;g2++)
      gload_lds16(bSrc[g2] + k0, Bs + (w*BPW+g2)*512);
    __syncthreads();
    bf16x8 aF[4], bF[FN];
    #pragma unroll
    for(int i=0;i<4;i++)
      aF[i] = *(const bf16x8*)(As + (wrow*4+i)*512 + lane*8);
    #pragma unroll
    for(int j=0;j<FN;j++)
      bF[j] = *(const bf16x8*)(Bs + (wcol*FN+j)*512 + lane*8);
    #pragma unroll
    for(int i=0;i<4;i++)
      #pragma unroll
      for(int j=0;j<FN;j++)
        acc[i][j] = __builtin_amdgcn_mfma_f32_16x16x32_bf16(aF[i], bF[j], acc[i][j], 0, 0, 0);
    __syncthreads();
  }

  #pragma unroll
  for(int i=0;i<4;i++){
    int m0 = row0 + wrow*64 + i*16 + q*4;
    #pragma unroll
    for(int j=0;j<FN;j++){
      int n = col0 + wcol*(BN/2) + j*16 + r;
      float* cp = C + (size_t)m0*N + n;
      if(EPI==2){
        float bv = bias[n];
        #pragma unroll
        for(int p=0;p<4;p++) cp[(size_t)p*N] = softplusf(acc[i][j][p] + bv);
      } else {
        #pragma unroll
        for(int p=0;p<4;p++){
          float v = ACC ? cp[(size_t)p*N] + acc[i][j][p] : acc[i][j][p];
          cp[(size_t)p*N] = v;
          if(EPI==1) Cb[(size_t)(m0+p)*N + n] = (__bf16)v;
        }
      }
    }
  }
}

// ---------------------------------------------------------------------------
// in_proj GEMM (128x128 tile, K=512, N=2048) with fused conv(4)+SiLU epilogue.
// u-blocks (col0<1024): causal conv across the 16-token groups via LDS,
//   writes uc f32 + ucb bf16 in SCAN order. z-blocks: silu(z) bf16 in TOKEN order.
// ---------------------------------------------------------------------------
__global__ __launch_bounds__(256) void mfma_inproj_conv(
    const __bf16* __restrict__ A, const __bf16* __restrict__ Bt,
    const float* __restrict__ cw, const float* __restrict__ cb,
    float* __restrict__ uc, __bf16* __restrict__ ucb,
    __bf16* __restrict__ szb, int dir)
{
  constexpr int LDA = 512, LDB = 512, N = 2048, K = 512;
  __shared__ __align__(16) __bf16 As[8*512];
  __shared__ __align__(16) __bf16 Bs[8*512];
  __shared__ float cbuf[4][16][17];
  int tid  = threadIdx.x;
  int lane = tid & 63, w = tid >> 6;
  int wrow = w >> 1, wcol = w & 1;
  int r = lane & 15, q = lane >> 4;
  int row0 = blockIdx.y*128, col0 = blockIdx.x*128;

  f32x4 acc[4][4];
  #pragma unroll
  for(int i=0;i<4;i++)
    #pragma unroll
    for(int j=0;j<4;j++) acc[i][j] = (f32x4)0.f;

  const __bf16* aSrc[2];
  #pragma unroll
  for(int g2=0;g2<2;g2++)
    aSrc[g2] = A + (size_t)(row0 + (w*2+g2)*16 + r)*LDA + q*8;
  const __bf16* bSrc[2];
  #pragma unroll
  for(int g2=0;g2<2;g2++)
    bSrc[g2] = Bt + (size_t)(col0 + (w*2+g2)*16 + r)*LDB + q*8;

  for(int k0=0;k0<K;k0+=32){
    #pragma unroll
    for(int g2=0;g2<2;g2++)
      gload_lds16(aSrc[g2] + k0, As + (w*2+g2)*512);
    #pragma unroll
    for(int g2=0;g2<2;g2++)
      gload_lds16(bSrc[g2] + k0, Bs + (w*2+g2)*512);
    __syncthreads();
    bf16x8 aF[4], bF[4];
    #pragma unroll
    for(int i=0;i<4;i++)
      aF[i] = *(const bf16x8*)(As + (wrow*4+i)*512 + lane*8);
    #pragma unroll
    for(int j=0;j<4;j++)
      bF[j] = *(const bf16x8*)(Bs + (wcol*4+j)*512 + lane*8);
    #pragma unroll
    for(int i=0;i<4;i++)
      #pragma unroll
      for(int j=0;j<4;j++)
        acc[i][j] = __builtin_amdgcn_mfma_f32_16x16x32_bf16(aF[i], bF[j], acc[i][j], 0, 0, 0);
    __syncthreads();
  }

  bool is_u = (col0 < 1024);
  #pragma unroll
  for(int i=0;i<4;i++){
    int seq = row0 + wrow*64 + i*16;     // = b*16 (token-row base)
    #pragma unroll
    for(int j=0;j<4;j++){
      int nb = col0 + wcol*64 + j*16;
      if(is_u){
        #pragma unroll
        for(int p=0;p<4;p++) cbuf[w][q*4+p][r] = acc[i][j][p];
        __syncthreads();
        int d = nb + r;
        float4 w4 = ((const float4*)cw)[d];
        float bv = cb[d];
        #pragma unroll
        for(int p=0;p<4;p++){
          int t = q*4+p;                 // scan step
          float v = bv;
          #pragma unroll
          for(int k=0;k<4;k++){
            int ss = t + k - 3;          // source scan step
            int tk = dir ? (15-ss) : ss; // source token row
            float uval = (ss>=0) ? cbuf[w][tk][r] : 0.f;
            v += ((const float*)&w4)[k] * uval;
          }
          float s = siluf(v);
          size_t o = (size_t)(seq + t)*1024 + d;
          uc[o] = s; ucb[o] = (__bf16)s;
        }
        __syncthreads();
      } else {
        int dz = nb + r - 1024;
        #pragma unroll
        for(int p=0;p<4;p++){
          int token = q*4+p;
          szb[(size_t)(seq+token)*1024 + dz] = (__bf16)siluf(acc[i][j][p]);
        }
      }
    }
  }
}

// ---------------------------------------------------------------------------
// bias + LN + pos
// ---------------------------------------------------------------------------
__global__ __launch_bounds__(256) void ln_pos_kernel(
    const float* __restrict__ in, const float* __restrict__ pb,
    const float* __restrict__ g, const float* __restrict__ bt,
    const float* __restrict__ pos, float* __restrict__ out)
{
  __shared__ float sred[4];
  int row = blockIdx.x; int l = row & 15; int tid = threadIdx.x;
  const float* ip = in + (size_t)row*512;
  float v0 = ip[tid] + pb[tid], v1 = ip[tid+256] + pb[tid+256];
  float s = block_reduce_sum(v0+v1, sred);
  float mean = s * (1.f/512.f);
  float d0 = v0-mean, d1 = v1-mean;
  float vs = block_reduce_sum(d0*d0+d1*d1, sred);
  float rstd = rsqrtf(vs*(1.f/512.f) + EPS);
  out[(size_t)row*512+tid]     = d0*rstd*g[tid]     + bt[tid]     + pos[l*512+tid];
  out[(size_t)row*512+tid+256] = d1*rstd*g[tid+256] + bt[tid+256] + pos[l*512+tid+256];
}

__global__ __launch_bounds__(256) void ln_bf16_kernel(
    const float* __restrict__ in, const float* __restrict__ g,
    const float* __restrict__ bt, __bf16* __restrict__ out)
{
  __shared__ float sred[4];
  int row = blockIdx.x; int tid = threadIdx.x;
  const float* ip = in + (size_t)row*512;
  float v0 = ip[tid], v1 = ip[tid+256];
  float s = block_reduce_sum(v0+v1, sred);
  float mean = s * (1.f/512.f);
  float d0 = v0-mean, d1 = v1-mean;
  float vs = block_reduce_sum(d0*d0+d1*d1, sred);
  float rstd = rsqrtf(vs*(1.f/512.f) + EPS);
  out[(size_t)row*512+tid]     = (__bf16)(d0*rstd*g[tid]     + bt[tid]);
  out[(size_t)row*512+tid+256] = (__bf16)(d1*rstd*g[tid+256] + bt[tid+256]);
}

__global__ __launch_bounds__(256) void ln_f32_kernel(
    const float* __restrict__ in, const float* __restrict__ g,
    const float* __restrict__ bt, float* __restrict__ out)
{
  __shared__ float sred[4];
  int row = blockIdx.x; int tid = threadIdx.x;
  const float* ip = in + (size_t)row*512;
  float v0 = ip[tid], v1 = ip[tid+256];
  float s = block_reduce_sum(v0+v1, sred);
  float mean = s * (1.f/512.f);
  float d0 = v0-mean, d1 = v1-mean;
  float vs = block_reduce_sum(d0*d0+d1*d1, sred);
  float rstd = rsqrtf(vs*(1.f/512.f) + EPS);
  out[(size_t)row*512+tid]     = d0*rstd*g[tid]     + bt[tid];
  out[(size_t)row*512+tid+256] = d1*rstd*g[tid+256] + bt[tid+256];
}

// ---------------------------------------------------------------------------
// selective scan (dt precomputed via GEMM+softplus) + skip + gate -> gb (bf16)
// one thread per (b,d); 16 states in regs.
// ---------------------------------------------------------------------------
__global__ __launch_bounds__(256) void scan_kernel(
    const float* __restrict__ dtb, const float* __restrict__ uc_in,
    const float* __restrict__ proj, const __bf16* __restrict__ szb,
    const float* __restrict__ A_log, const float* __restrict__ Dskip,
    __bf16* __restrict__ g_out, int dir)
{
  int b = blockIdx.x;
  int d = blockIdx.y*256 + threadIdx.x;
  __shared__ float sB[16][16], sC[16][16];
  int tid = threadIdx.x;
  {
    int t = tid >> 4, n = tid & 15;
    sB[t][n] = proj[(size_t)(b*16+t)*64 + 32 + n];
    sC[t][n] = proj[(size_t)(b*16+t)*64 + 48 + n];
  }
  __syncthreads();
  float a[16], hst[16];
  #pragma unroll
  for(int n=0;n<16;n++){ a[n] = -__expf(A_log[d*16+n]); hst[n]=0.f; }
  float Dv = Dskip[d];
  for(int t=0;t<16;t++){
    float dtv = dtb[(size_t)(b*16+t)*1024 + d];
    float ucv = uc_in[(size_t)(b*16+t)*1024 + d];
    float dtu = dtv*ucv;
    float y = 0.f;
    #pragma unroll
    for(int n=0;n<16;n++){
      hst[n] = __expf(dtv*a[n])*hst[n] + dtu*sB[t][n];
      y += hst[n]*sC[t][n];
    }
    int tok = dir ? (15-t) : t;
    float zs = (float)szb[(size_t)(b*16+tok)*1024 + d];
    g_out[(size_t)(b*16+tok)*1024 + d] = (__bf16)((y + ucv*Dv) * zs);
  }
}

// ---------------------------------------------------------------------------
extern "C" void kernel_launch(void* const* d_in, const int* in_sizes, int n_in,
                              void* d_out, int out_size, void* d_ws, size_t ws_size,
                              hipStream_t stream) {
  (void)in_sizes; (void)n_in; (void)out_size; (void)ws_size;
  const float* x         = (const float*)d_in[0];
  const float* bn_gamma  = (const float*)d_in[1];
  const float* bn_beta   = (const float*)d_in[2];
  const float* bn_mean   = (const float*)d_in[3];
  const float* bn_var    = (const float*)d_in[4];
  const float* patch_w   = (const float*)d_in[5];
  const float* patch_b   = (const float*)d_in[6];
  const float* ln_pg     = (const float*)d_in[7];
  const float* ln_pb     = (const float*)d_in[8];
  const float* pos       = (const float*)d_in[9];
  const float* blk_ln_g  = (const float*)d_in[10];
  const float* blk_ln_b  = (const float*)d_in[11];
  const float* in_proj_w = (const float*)d_in[12];
  const float* conv_w    = (const float*)d_in[13];
  const float* conv_b    = (const float*)d_in[14];
  const float* x_proj_w  = (const float*)d_in[15];
  const float* dt_proj_w = (const float*)d_in[16];
  const float* dt_proj_b = (const float*)d_in[17];
  const float* A_log     = (const float*)d_in[18];
  const float* Dskip     = (const float*)d_in[19];
  const float* out_proj_w= (const float*)d_in[20];
  const float* fin_g     = (const float*)d_in[21];
  const float* fin_b     = (const float*)d_in[22];

  char* p = (char*)d_ws;
  float*  h    = (float*)p;  p += (size_t)NROWS*512*4;    // 8 MB
  float*  uc   = (float*)p;  p += (size_t)NROWS*1024*4;   // 16 MB (also patch scratch)
  float*  dtb  = (float*)p;  p += (size_t)NROWS*1024*4;   // 16 MB
  float*  proj = (float*)p;  p += (size_t)NROWS*64*4;     // 1 MB
  __bf16* hnb  = (__bf16*)p; p += (size_t)NROWS*512*2;    // 4 MB
  __bf16* ucb  = (__bf16*)p; p += (size_t)NROWS*1024*2;   // 8 MB
  __bf16* szb  = (__bf16*)p; p += (size_t)NROWS*1024*2;   // 8 MB
  __bf16* gb   = (__bf16*)p; p += (size_t)NROWS*1024*2;   // 8 MB
  __bf16* projb= (__bf16*)p; p += (size_t)NROWS*64*2;     // 0.5 MB
  __bf16* wtin = (__bf16*)p; p += (size_t)4*2048*512*2;   // 8 MB
  __bf16* wtout= (__bf16*)p; p += (size_t)4*512*1024*2;   // 4 MB
  __bf16* wtx  = (__bf16*)p; p += (size_t)4*64*1024*2;    // 0.5 MB
  __bf16* wdtT = (__bf16*)p; p += (size_t)4*1024*32*2;    // 0.25 MB
  __bf16* Abuf = (__bf16*)p; p += (size_t)NROWS*KPAD*2;   // 0.75 MB
  __bf16* pwb  = (__bf16*)p; p += (size_t)512*KPAD*2;     // 96 KB

  // weight prep
  transpose_bf16_kernel<<<dim3(64, 16, 4), dim3(32,8), 0, stream>>>(
      in_proj_w, wtin, 512, 2048);
  transpose_bf16_kernel<<<dim3(16, 32, 4), dim3(32,8), 0, stream>>>(
      out_proj_w, wtout, 1024, 512);
  transpose_bf16_kernel<<<dim3(2, 32, 4), dim3(32,8), 0, stream>>>(
      x_proj_w, wtx, 1024, 64);
  transpose_bf16_kernel<<<dim3(32, 1, 4), dim3(32,8), 0, stream>>>(
      dt_proj_w, wdtT, 32, 1024);
  cast_pad_pw_kernel<<<(512*KPAD + 255)/256, 256, 0, stream>>>(patch_w, pwb);

  // patch embed via MFMA (scratch = uc region)
  bn_patchify_kernel<<<(NROWS*KPAD)/256, 256, 0, stream>>>(
      x, bn_gamma, bn_beta, bn_mean, bn_var, Abuf);
  mfma_gemm<128,0,0><<<dim3(4, 32), 256, 0, stream>>>(
      Abuf, pwb, uc, nullptr, nullptr, NROWS, 512, KPAD, KPAD, KPAD);
  ln_pos_kernel<<<NROWS, 256, 0, stream>>>(uc, patch_b, ln_pg, ln_pb, pos, h);

  for(int i=0;i<2;i++){
    ln_bf16_kernel<<<NROWS, 256, 0, stream>>>(h, blk_ln_g + i*512, blk_ln_b + i*512, hnb);
    for(int dir=0;dir<2;dir++){
      size_t off = (size_t)(i*2+dir);
      // in_proj + conv + silu fused
      mfma_inproj_conv<<<dim3(16, 32), 256, 0, stream>>>(
          hnb, wtin + off*2048*512, conv_w + off*1024*4, conv_b + off*1024,
          uc, ucb, szb, dir);
      // x_proj -> proj f32 + projb bf16
      mfma_gemm<64,0,1><<<dim3(1, 32), 256, 0, stream>>>(
          ucb, wtx + off*64*1024, proj, projb, nullptr, NROWS, 64, 1024, 1024, 1024);
      // dt = softplus(dtr @ Wdt + bdt)
      mfma_gemm<128,0,2><<<dim3(8, 32), 256, 0, stream>>>(
          projb, wdtT + off*1024*32, dtb, nullptr, dt_proj_b + off*1024,
          NROWS, 1024, 32, 64, 32);
      // selective scan + gate
      scan_kernel<<<dim3(BB,4), 256, 0, stream>>>(
          dtb, uc, proj, szb, A_log + off*1024*16, Dskip + off*1024, gb, dir);
      // out_proj accumulate into h
      mfma_gemm<64,1,0><<<dim3(8, 32), 256, 0, stream>>>(
          gb, wtout + off*512*1024, h, nullptr, nullptr, NROWS, 512, 1024, 1024, 1024);
    }
  }
  ln_f32_kernel<<<NROWS, 256, 0, stream>>>(h, fin_g, fin_b, (float*)d_out);
}

// Round 5
// 560.510 us; speedup vs baseline: 1.2539x; 1.2539x over previous
//
#include <hip/hip_runtime.h>
#include <math.h>
#include <stdint.h>

#define BB 256
#define C_IN 7
#define TT 160
#define PATCH 10
#define D_MODEL 512
#define L_TOK 16
#define D_INNER 1024
#define D_STATE 16
#define DT_RANK 32
#define EPS 1e-5f
#define NROWS (BB*L_TOK)   // 4096
#define KPAD 96            // 70 padded to 3*32

typedef __bf16 bf16x8 __attribute__((ext_vector_type(8)));
typedef float  f32x4  __attribute__((ext_vector_type(4)));

__device__ __forceinline__ float siluf(float x){ return x / (1.f + __expf(-x)); }
__device__ __forceinline__ float softplusf(float x){ return (x > 20.f) ? x : log1pf(__expf(x)); }

__device__ __forceinline__ void gload_lds16(const void* gp, void* lp){
  __builtin_amdgcn_global_load_lds(
      (const __attribute__((address_space(1))) unsigned int*)(uintptr_t)gp,
      (__attribute__((address_space(3))) unsigned int*)(uintptr_t)lp, 16, 0, 0);
}

__device__ __forceinline__ float block_reduce_sum(float v, float* sred4){
  for(int off=32; off>0; off>>=1) v += __shfl_down(v, off, 64);
  int lane = threadIdx.x & 63, wid = threadIdx.x >> 6;
  if(lane==0) sred4[wid] = v;
  __syncthreads();
  if(threadIdx.x==0) sred4[0] = sred4[0]+sred4[1]+sred4[2]+sred4[3];
  __syncthreads();
  float r = sred4[0];
  __syncthreads();
  return r;
}

// ---------------------------------------------------------------------------
// transpose + fp32->bf16: in [z][K][N] f32 -> out [z][N][K] bf16
// ---------------------------------------------------------------------------
__global__ __launch_bounds__(256) void transpose_bf16_kernel(
    const float* __restrict__ in, __bf16* __restrict__ out, int K, int N)
{
  __shared__ float tile[32][33];
  size_t moff = (size_t)blockIdx.z * K * N;
  int n0 = blockIdx.x*32, k0 = blockIdx.y*32;
  int tx = threadIdx.x, ty = threadIdx.y;
  #pragma unroll
  for(int rr=0;rr<4;rr++)
    tile[ty+rr*8][tx] = in[moff + (size_t)(k0+ty+rr*8)*N + n0+tx];
  __syncthreads();
  #pragma unroll
  for(int rr=0;rr<4;rr++)
    out[moff + (size_t)(n0+ty+rr*8)*K + k0+tx] = (__bf16)tile[tx][ty+rr*8];
}

// out_proj K-concat transpose: in [layer][dir][1024][512] f32 ->
// out [layer][512][2048] bf16 with out[n][dir*1024+k] = in[l][dir][k][n]
__global__ __launch_bounds__(256) void transpose_outw_kernel(
    const float* __restrict__ in, __bf16* __restrict__ out)
{
  __shared__ float tile[32][33];
  int z = blockIdx.z, layer = z>>1, dir = z&1;
  int n0 = blockIdx.x*32, k0 = blockIdx.y*32;
  int tx = threadIdx.x, ty = threadIdx.y;
  const float* ip = in + (size_t)z*1024*512;
  #pragma unroll
  for(int rr=0;rr<4;rr++)
    tile[ty+rr*8][tx] = ip[(size_t)(k0+ty+rr*8)*512 + n0+tx];
  __syncthreads();
  __bf16* op = out + (size_t)layer*512*2048 + (size_t)dir*1024;
  #pragma unroll
  for(int rr=0;rr<4;rr++)
    op[(size_t)(n0+ty+rr*8)*2048 + k0+tx] = (__bf16)tile[tx][ty+rr*8];
}

// ---------------------------------------------------------------------------
// BN + patchify -> A[4096][96] bf16 (k>=70 zero-padded)
// ---------------------------------------------------------------------------
__global__ __launch_bounds__(256) void bn_patchify_kernel(
    const float* __restrict__ x, const float* __restrict__ bng,
    const float* __restrict__ bnb, const float* __restrict__ bnm,
    const float* __restrict__ bnv, __bf16* __restrict__ Abuf)
{
  int idx = blockIdx.x*256 + threadIdx.x;
  int row = idx / KPAD, k = idx % KPAD;
  int b = row >> 4, l = row & 15;
  float v = 0.f;
  if(k < C_IN*PATCH){
    int c = k / PATCH, j = k % PATCH;
    float xv = x[(b*C_IN + c)*TT + l*PATCH + j];
    v = (xv - bnm[c]) * rsqrtf(bnv[c] + EPS) * bng[c] + bnb[c];
  }
  Abuf[idx] = (__bf16)v;
}

__global__ __launch_bounds__(256) void cast_pad_pw_kernel(
    const float* __restrict__ pw, __bf16* __restrict__ pwb)
{
  int idx = blockIdx.x*256 + threadIdx.x;
  if(idx >= 512*KPAD) return;
  int n = idx / KPAD, k = idx % KPAD;
  pwb[idx] = (__bf16)(k < C_IN*PATCH ? pw[n*(C_IN*PATCH) + k] : 0.f);
}

// ---------------------------------------------------------------------------
// Generic MFMA bf16 GEMM, batched over blockIdx.z via byte-element strides.
// C[M,N](f32) (+)= A[M,K]@Bt[N,K]^T.  EPI: 0 plain; 1 dual f32+bf16; 2 softplus+bias.
// ---------------------------------------------------------------------------
template<int BN, int ACC, int EPI>
__global__ __launch_bounds__(256) void mfma_gemm(
    const __bf16* __restrict__ A, const __bf16* __restrict__ Bt,
    float* __restrict__ C, __bf16* __restrict__ Cb,
    const float* __restrict__ bias, int N, int K, int lda, int ldb,
    size_t sA, size_t sB, size_t sC, size_t sBias)
{
  constexpr int NGB = BN/16;
  constexpr int FN  = BN/32;
  constexpr int BPW = NGB/4;
  __shared__ __align__(16) __bf16 As[8*512];
  __shared__ __align__(16) __bf16 Bs[NGB*512];
  int z = blockIdx.z;
  A  += (size_t)z*sA;  Bt += (size_t)z*sB;  C += (size_t)z*sC;
  if(EPI==1) Cb += (size_t)z*sC;
  if(EPI==2) bias += (size_t)z*sBias;
  int tid  = threadIdx.x;
  int lane = tid & 63, w = tid >> 6;
  int wrow = w >> 1, wcol = w & 1;
  int r = lane & 15, q = lane >> 4;
  int row0 = blockIdx.y*128, col0 = blockIdx.x*BN;

  f32x4 acc[4][FN];
  #pragma unroll
  for(int i=0;i<4;i++)
    #pragma unroll
    for(int j=0;j<FN;j++) acc[i][j] = (f32x4)0.f;

  const __bf16* aSrc[2];
  #pragma unroll
  for(int g2=0;g2<2;g2++)
    aSrc[g2] = A + (size_t)(row0 + (w*2+g2)*16 + r)*lda + q*8;
  const __bf16* bSrc[BPW];
  #pragma unroll
  for(int g2=0;g2<BPW;g2++)
    bSrc[g2] = Bt + (size_t)(col0 + (w*BPW+g2)*16 + r)*ldb + q*8;

  for(int k0=0;k0<K;k0+=32){
    #pragma unroll
    for(int g2=0;g2<2;g2++)
      gload_lds16(aSrc[g2] + k0, As + (w*2+g2)*512);
    #pragma unroll
    for(int g2=0;g2<BPW;g2++)
      gload_lds16(bSrc[g2] + k0, Bs + (w*BPW+g2)*512);
    __syncthreads();
    bf16x8 aF[4], bF[FN];
    #pragma unroll
    for(int i=0;i<4;i++)
      aF[i] = *(const bf16x8*)(As + (wrow*4+i)*512 + lane*8);
    #pragma unroll
    for(int j=0;j<FN;j++)
      bF[j] = *(const bf16x8*)(Bs + (wcol*FN+j)*512 + lane*8);
    #pragma unroll
    for(int i=0;i<4;i++)
      #pragma unroll
      for(int j=0;j<FN;j++)
        acc[i][j] = __builtin_amdgcn_mfma_f32_16x16x32_bf16(aF[i], bF[j], acc[i][j], 0, 0, 0);
    __syncthreads();
  }

  #pragma unroll
  for(int i=0;i<4;i++){
    int m0 = row0 + wrow*64 + i*16 + q*4;
    #pragma unroll
    for(int j=0;j<FN;j++){
      int n = col0 + wcol*(BN/2) + j*16 + r;
      float* cp = C + (size_t)m0*N + n;
      if(EPI==2){
        float bv = bias[n];
        #pragma unroll
        for(int p=0;p<4;p++) cp[(size_t)p*N] = softplusf(acc[i][j][p] + bv);
      } else {
        #pragma unroll
        for(int p=0;p<4;p++){
          float v = ACC ? cp[(size_t)p*N] + acc[i][j][p] : acc[i][j][p];
          cp[(size_t)p*N] = v;
          if(EPI==1) Cb[(size_t)(m0+p)*N + n] = (__bf16)v;
        }
      }
    }
  }
}

// ---------------------------------------------------------------------------
// in_proj GEMM, both dirs N-concat (N=4096, K=512, grid 32x32) with fused
// conv(4)+SiLU epilogue via lane shuffles (barrier-free). All outputs token
// order: uc/ucb (u path), szb (silu(z) path), each [dir][4096][1024].
// ---------------------------------------------------------------------------
__global__ __launch_bounds__(256) void mfma_inproj_conv(
    const __bf16* __restrict__ A, const __bf16* __restrict__ Bt,
    const float* __restrict__ cw, const float* __restrict__ cb,
    float* __restrict__ uc, __bf16* __restrict__ ucb, __bf16* __restrict__ szb)
{
  constexpr int LDA = 512, LDB = 512, K = 512;
  __shared__ __align__(16) __bf16 As[8*512];
  __shared__ __align__(16) __bf16 Bs[8*512];
  int tid  = threadIdx.x;
  int lane = tid & 63, w = tid >> 6;
  int wrow = w >> 1, wcol = w & 1;
  int r = lane & 15, q = lane >> 4;
  int row0 = blockIdx.y*128, col0 = blockIdx.x*128;

  f32x4 acc[4][4];
  #pragma unroll
  for(int i=0;i<4;i++)
    #pragma unroll
    for(int j=0;j<4;j++) acc[i][j] = (f32x4)0.f;

  const __bf16* aSrc[2];
  #pragma unroll
  for(int g2=0;g2<2;g2++)
    aSrc[g2] = A + (size_t)(row0 + (w*2+g2)*16 + r)*LDA + q*8;
  const __bf16* bSrc[2];
  #pragma unroll
  for(int g2=0;g2<2;g2++)
    bSrc[g2] = Bt + (size_t)(col0 + (w*2+g2)*16 + r)*LDB + q*8;

  for(int k0=0;k0<K;k0+=32){
    #pragma unroll
    for(int g2=0;g2<2;g2++)
      gload_lds16(aSrc[g2] + k0, As + (w*2+g2)*512);
    #pragma unroll
    for(int g2=0;g2<2;g2++)
      gload_lds16(bSrc[g2] + k0, Bs + (w*2+g2)*512);
    __syncthreads();
    bf16x8 aF[4], bF[4];
    #pragma unroll
    for(int i=0;i<4;i++)
      aF[i] = *(const bf16x8*)(As + (wrow*4+i)*512 + lane*8);
    #pragma unroll
    for(int j=0;j<4;j++)
      bF[j] = *(const bf16x8*)(Bs + (wcol*4+j)*512 + lane*8);
    #pragma unroll
    for(int i=0;i<4;i++)
      #pragma unroll
      for(int j=0;j<4;j++)
        acc[i][j] = __builtin_amdgcn_mfma_f32_16x16x32_bf16(aF[i], bF[j], acc[i][j], 0, 0, 0);
    __syncthreads();
  }

  int dirq = col0 >> 11;                 // 0: cols [0,2048), 1: [2048,4096)
  bool is_u = (col0 & 2047) < 1024;      // block-uniform
  int dbase = (col0 & 1023) + wcol*64;
  const float* cwd = cw + dirq*4096;
  const float* cbd = cb + dirq*1024;
  float*  ucD  = uc  + (size_t)dirq*NROWS*1024;
  __bf16* ucbD = ucb + (size_t)dirq*NROWS*1024;
  __bf16* szD  = szb + (size_t)dirq*NROWS*1024;

  #pragma unroll
  for(int i=0;i<4;i++){
    int seq = row0 + wrow*64 + i*16;     // multiple of 16 = b*16
    #pragma unroll
    for(int j=0;j<4;j++){
      int dloc = dbase + j*16 + r;
      float A0=acc[i][j][0], A1=acc[i][j][1], A2=acc[i][j][2], A3=acc[i][j][3];
      if(is_u){
        float4 w4 = ((const float4*)cwd)[dloc];   // {w0,w1,w2,w3}
        float bv = cbd[dloc];
        float cur[4]={A0,A1,A2,A3};
        float vout[4];
        if(dirq==0){
          // taps u[t-m], m=1..3: same-lane lower reg, or lane-16 high regs
          float S1=__shfl_up(A1,16,64), S2=__shfl_up(A2,16,64), S3=__shfl_up(A3,16,64);
          float um1[4]={S3,A0,A1,A2};
          float um2[4]={S2,S3,A0,A1};
          float um3[4]={S1,S2,S3,A0};
          #pragma unroll
          for(int p=0;p<4;p++){
            int t=q*4+p;
            float v = bv + w4.w*cur[p];
            v += (t>=1)? w4.z*um1[p] : 0.f;
            v += (t>=2)? w4.y*um2[p] : 0.f;
            v += (t>=3)? w4.x*um3[p] : 0.f;
            vout[p]=v;
          }
        } else {
          // dir1 in token space: taps u[t+m] with weight w[3-m]
          float D0=__shfl_down(A0,16,64), D1=__shfl_down(A1,16,64), D2=__shfl_down(A2,16,64);
          float up1[4]={A1,A2,A3,D0};
          float up2[4]={A2,A3,D0,D1};
          float up3[4]={A3,D0,D1,D2};
          #pragma unroll
          for(int p=0;p<4;p++){
            int t=q*4+p;
            float v = bv + w4.w*cur[p];
            v += (t<=14)? w4.z*up1[p] : 0.f;
            v += (t<=13)? w4.y*up2[p] : 0.f;
            v += (t<=12)? w4.x*up3[p] : 0.f;
            vout[p]=v;
          }
        }
        #pragma unroll
        for(int p=0;p<4;p++){
          float s = siluf(vout[p]);
          size_t o = (size_t)(seq + q*4+p)*1024 + dloc;
          ucD[o] = s; ucbD[o] = (__bf16)s;
        }
      } else {
        #pragma unroll
        for(int p=0;p<4;p++)
          szD[(size_t)(seq + q*4+p)*1024 + dloc] = (__bf16)siluf(acc[i][j][p]);
      }
    }
  }
}

// ---------------------------------------------------------------------------
// bias + LN + pos
// ---------------------------------------------------------------------------
__global__ __launch_bounds__(256) void ln_pos_kernel(
    const float* __restrict__ in, const float* __restrict__ pb,
    const float* __restrict__ g, const float* __restrict__ bt,
    const float* __restrict__ pos, float* __restrict__ out)
{
  __shared__ float sred[4];
  int row = blockIdx.x; int l = row & 15; int tid = threadIdx.x;
  const float* ip = in + (size_t)row*512;
  float v0 = ip[tid] + pb[tid], v1 = ip[tid+256] + pb[tid+256];
  float s = block_reduce_sum(v0+v1, sred);
  float mean = s * (1.f/512.f);
  float d0 = v0-mean, d1 = v1-mean;
  float vs = block_reduce_sum(d0*d0+d1*d1, sred);
  float rstd = rsqrtf(vs*(1.f/512.f) + EPS);
  out[(size_t)row*512+tid]     = d0*rstd*g[tid]     + bt[tid]     + pos[l*512+tid];
  out[(size_t)row*512+tid+256] = d1*rstd*g[tid+256] + bt[tid+256] + pos[l*512+tid+256];
}

__global__ __launch_bounds__(256) void ln_bf16_kernel(
    const float* __restrict__ in, const float* __restrict__ g,
    const float* __restrict__ bt, __bf16* __restrict__ out)
{
  __shared__ float sred[4];
  int row = blockIdx.x; int tid = threadIdx.x;
  const float* ip = in + (size_t)row*512;
  float v0 = ip[tid], v1 = ip[tid+256];
  float s = block_reduce_sum(v0+v1, sred);
  float mean = s * (1.f/512.f);
  float d0 = v0-mean, d1 = v1-mean;
  float vs = block_reduce_sum(d0*d0+d1*d1, sred);
  float rstd = rsqrtf(vs*(1.f/512.f) + EPS);
  out[(size_t)row*512+tid]     = (__bf16)(d0*rstd*g[tid]     + bt[tid]);
  out[(size_t)row*512+tid+256] = (__bf16)(d1*rstd*g[tid+256] + bt[tid+256]);
}

__global__ __launch_bounds__(256) void ln_f32_kernel(
    const float* __restrict__ in, const float* __restrict__ g,
    const float* __restrict__ bt, float* __restrict__ out)
{
  __shared__ float sred[4];
  int row = blockIdx.x; int tid = threadIdx.x;
  const float* ip = in + (size_t)row*512;
  float v0 = ip[tid], v1 = ip[tid+256];
  float s = block_reduce_sum(v0+v1, sred);
  float mean = s * (1.f/512.f);
  float d0 = v0-mean, d1 = v1-mean;
  float vs = block_reduce_sum(d0*d0+d1*d1, sred);
  float rstd = rsqrtf(vs*(1.f/512.f) + EPS);
  out[(size_t)row*512+tid]     = d0*rstd*g[tid]     + bt[tid];
  out[(size_t)row*512+tid+256] = d1*rstd*g[tid+256] + bt[tid+256];
}

// ---------------------------------------------------------------------------
// selective scan, both dirs (gridDim.y=8: dir = y>>2). All inputs token order;
// scan maps step s -> token. gb out: [row][2048] K-concat for out_proj.
// ---------------------------------------------------------------------------
__global__ __launch_bounds__(256) void scan_kernel(
    const float* __restrict__ dtb, const float* __restrict__ uc,
    const float* __restrict__ proj, const __bf16* __restrict__ szb,
    const float* __restrict__ A_log, const float* __restrict__ Dskip,
    __bf16* __restrict__ gb)
{
  int b = blockIdx.x;
  int dirq = blockIdx.y >> 2;
  int d = (blockIdx.y & 3)*256 + threadIdx.x;
  const float*  dtp = dtb  + (size_t)dirq*NROWS*1024;
  const float*  ucp = uc   + (size_t)dirq*NROWS*1024;
  const float*  prp = proj + (size_t)dirq*NROWS*64;
  const __bf16* szp = szb  + (size_t)dirq*NROWS*1024;
  const float*  Alp = A_log + (size_t)dirq*1024*16;
  float Dv = Dskip[dirq*1024 + d];
  __shared__ float sB[16][16], sC[16][16];
  {
    int s = threadIdx.x >> 4, n = threadIdx.x & 15;
    int tok = dirq ? 15-s : s;
    sB[s][n] = prp[(size_t)(b*16+tok)*64 + 32 + n];
    sC[s][n] = prp[(size_t)(b*16+tok)*64 + 48 + n];
  }
  __syncthreads();
  float a[16], hst[16];
  #pragma unroll
  for(int n=0;n<16;n++){ a[n] = -__expf(Alp[d*16+n]); hst[n]=0.f; }
  for(int s=0;s<16;s++){
    int tok = dirq ? 15-s : s;
    size_t o = (size_t)(b*16+tok)*1024 + d;
    float dtv = dtp[o];
    float ucv = ucp[o];
    float dtu = dtv*ucv;
    float y = 0.f;
    #pragma unroll
    for(int n=0;n<16;n++){
      hst[n] = __expf(dtv*a[n])*hst[n] + dtu*sB[s][n];
      y += hst[n]*sC[s][n];
    }
    float zs = (float)szp[o];
    gb[(size_t)(b*16+tok)*2048 + dirq*1024 + d] = (__bf16)((y + ucv*Dv) * zs);
  }
}

// ---------------------------------------------------------------------------
extern "C" void kernel_launch(void* const* d_in, const int* in_sizes, int n_in,
                              void* d_out, int out_size, void* d_ws, size_t ws_size,
                              hipStream_t stream) {
  (void)in_sizes; (void)n_in; (void)out_size; (void)ws_size;
  const float* x         = (const float*)d_in[0];
  const float* bn_gamma  = (const float*)d_in[1];
  const float* bn_beta   = (const float*)d_in[2];
  const float* bn_mean   = (const float*)d_in[3];
  const float* bn_var    = (const float*)d_in[4];
  const float* patch_w   = (const float*)d_in[5];
  const float* patch_b   = (const float*)d_in[6];
  const float* ln_pg     = (const float*)d_in[7];
  const float* ln_pb     = (const float*)d_in[8];
  const float* pos       = (const float*)d_in[9];
  const float* blk_ln_g  = (const float*)d_in[10];
  const float* blk_ln_b  = (const float*)d_in[11];
  const float* in_proj_w = (const float*)d_in[12];
  const float* conv_w    = (const float*)d_in[13];
  const float* conv_b    = (const float*)d_in[14];
  const float* x_proj_w  = (const float*)d_in[15];
  const float* dt_proj_w = (const float*)d_in[16];
  const float* dt_proj_b = (const float*)d_in[17];
  const float* A_log     = (const float*)d_in[18];
  const float* Dskip     = (const float*)d_in[19];
  const float* out_proj_w= (const float*)d_in[20];
  const float* fin_g     = (const float*)d_in[21];
  const float* fin_b     = (const float*)d_in[22];

  char* p = (char*)d_ws;
  float*  h    = (float*)p;  p += (size_t)NROWS*512*4;      // 8 MB
  float*  uc2  = (float*)p;  p += (size_t)2*NROWS*1024*4;   // 32 MB
  float*  dtb2 = (float*)p;  p += (size_t)2*NROWS*1024*4;   // 32 MB (patch scratch too)
  float*  proj2= (float*)p;  p += (size_t)2*NROWS*64*4;     // 2 MB
  __bf16* hnb  = (__bf16*)p; p += (size_t)NROWS*512*2;      // 4 MB
  __bf16* ucb2 = (__bf16*)p; p += (size_t)2*NROWS*1024*2;   // 16 MB
  __bf16* szb2 = (__bf16*)p; p += (size_t)2*NROWS*1024*2;   // 16 MB
  __bf16* gbK  = (__bf16*)p; p += (size_t)NROWS*2048*2;     // 16 MB
  __bf16* projb2=(__bf16*)p; p += (size_t)2*NROWS*64*2;     // 1 MB
  __bf16* wtin = (__bf16*)p; p += (size_t)4*2048*512*2;     // 8 MB ([layer][4096][512])
  __bf16* wtoutK=(__bf16*)p; p += (size_t)2*512*2048*2;     // 4 MB ([layer][512][2048])
  __bf16* wtx  = (__bf16*)p; p += (size_t)4*64*1024*2;      // 0.5 MB
  __bf16* wdtT = (__bf16*)p; p += (size_t)4*1024*32*2;      // 0.25 MB
  __bf16* Abuf = (__bf16*)p; p += (size_t)NROWS*KPAD*2;     // 0.75 MB
  __bf16* pwb  = (__bf16*)p; p += (size_t)512*KPAD*2;       // 96 KB

  // ---- weight prep ----
  transpose_bf16_kernel<<<dim3(64, 16, 4), dim3(32,8), 0, stream>>>(
      in_proj_w, wtin, 512, 2048);                 // -> [layer][dir-concat 4096][512]
  transpose_outw_kernel<<<dim3(16, 32, 4), dim3(32,8), 0, stream>>>(
      out_proj_w, wtoutK);                         // -> [layer][512][K-concat 2048]
  transpose_bf16_kernel<<<dim3(2, 32, 4), dim3(32,8), 0, stream>>>(
      x_proj_w, wtx, 1024, 64);
  transpose_bf16_kernel<<<dim3(32, 1, 4), dim3(32,8), 0, stream>>>(
      dt_proj_w, wdtT, 32, 1024);
  cast_pad_pw_kernel<<<(512*KPAD + 255)/256, 256, 0, stream>>>(patch_w, pwb);

  // ---- patch embed (scratch = dtb2 region) ----
  bn_patchify_kernel<<<(NROWS*KPAD)/256, 256, 0, stream>>>(
      x, bn_gamma, bn_beta, bn_mean, bn_var, Abuf);
  mfma_gemm<128,0,0><<<dim3(4, 32, 1), 256, 0, stream>>>(
      Abuf, pwb, dtb2, nullptr, nullptr, 512, KPAD, KPAD, KPAD, 0,0,0,0);
  ln_pos_kernel<<<NROWS, 256, 0, stream>>>(dtb2, patch_b, ln_pg, ln_pb, pos, h);

  for(int i=0;i<2;i++){
    ln_bf16_kernel<<<NROWS, 256, 0, stream>>>(h, blk_ln_g + i*512, blk_ln_b + i*512, hnb);
    // in_proj both dirs + conv + silu (token order outputs)
    mfma_inproj_conv<<<dim3(32, 32), 256, 0, stream>>>(
        hnb, wtin + (size_t)i*4096*512, conv_w + (size_t)i*2*4096,
        conv_b + (size_t)i*2*1024, uc2, ucb2, szb2);
    // x_proj (z=2 dirs) -> proj f32 + projb bf16
    mfma_gemm<64,0,1><<<dim3(1, 32, 2), 256, 0, stream>>>(
        ucb2, wtx + (size_t)i*2*64*1024, proj2, projb2, nullptr,
        64, 1024, 1024, 1024,
        (size_t)NROWS*1024, (size_t)64*1024, (size_t)NROWS*64, 0);
    // dt = softplus(dtr @ Wdt + bias) (z=2 dirs)
    mfma_gemm<128,0,2><<<dim3(8, 32, 2), 256, 0, stream>>>(
        projb2, wdtT + (size_t)i*2*1024*32, dtb2, nullptr, dt_proj_b + (size_t)i*2*1024,
        1024, 32, 64, 32,
        (size_t)NROWS*64, (size_t)1024*32, (size_t)NROWS*1024, 1024);
    // scan both dirs -> gbK [row][2048]
    scan_kernel<<<dim3(BB, 8), 256, 0, stream>>>(
        dtb2, uc2, proj2, szb2, A_log + (size_t)i*2*1024*16,
        Dskip + (size_t)i*2*1024, gbK);
    // out_proj both dirs as one K=2048 GEMM, accumulate into h
    mfma_gemm<64,1,0><<<dim3(8, 32, 1), 256, 0, stream>>>(
        gbK, wtoutK + (size_t)i*512*2048, h, nullptr, nullptr,
        512, 2048, 2048, 2048, 0,0,0,0);
  }
  ln_f32_kernel<<<NROWS, 256, 0, stream>>>(h, fin_g, fin_b, (float*)d_out);
}

// Round 6
// 497.289 us; speedup vs baseline: 1.4133x; 1.1271x over previous
//
#include <hip/hip_runtime.h>
#include <math.h>
#include <stdint.h>

#define BB 256
#define C_IN 7
#define TT 160
#define PATCH 10
#define D_MODEL 512
#define L_TOK 16
#define D_INNER 1024
#define D_STATE 16
#define DT_RANK 32
#define EPS 1e-5f
#define NROWS (BB*L_TOK)   // 4096
#define KPAD 96            // 70 padded to 3*32

typedef __bf16 bf16x8 __attribute__((ext_vector_type(8)));
typedef __bf16 bf16x4 __attribute__((ext_vector_type(4)));
typedef float  f32x4  __attribute__((ext_vector_type(4)));

__device__ __forceinline__ float siluf(float x){ return x / (1.f + __expf(-x)); }
__device__ __forceinline__ float softplusf(float x){ return (x > 20.f) ? x : log1pf(__expf(x)); }

__device__ __forceinline__ void gload_lds16(const void* gp, void* lp){
  __builtin_amdgcn_global_load_lds(
      (const __attribute__((address_space(1))) unsigned int*)(uintptr_t)gp,
      (__attribute__((address_space(3))) unsigned int*)(uintptr_t)lp, 16, 0, 0);
}

__device__ __forceinline__ float block_reduce_sum(float v, float* sred4){
  for(int off=32; off>0; off>>=1) v += __shfl_down(v, off, 64);
  int lane = threadIdx.x & 63, wid = threadIdx.x >> 6;
  if(lane==0) sred4[wid] = v;
  __syncthreads();
  if(threadIdx.x==0) sred4[0] = sred4[0]+sred4[1]+sred4[2]+sred4[3];
  __syncthreads();
  float r = sred4[0];
  __syncthreads();
  return r;
}

// ---------------------------------------------------------------------------
// transpose + fp32->bf16: in [z][K][N] f32 -> out [z][N][K] bf16
// ---------------------------------------------------------------------------
__global__ __launch_bounds__(256) void transpose_bf16_kernel(
    const float* __restrict__ in, __bf16* __restrict__ out, int K, int N)
{
  __shared__ float tile[32][33];
  size_t moff = (size_t)blockIdx.z * K * N;
  int n0 = blockIdx.x*32, k0 = blockIdx.y*32;
  int tx = threadIdx.x, ty = threadIdx.y;
  #pragma unroll
  for(int rr=0;rr<4;rr++)
    tile[ty+rr*8][tx] = in[moff + (size_t)(k0+ty+rr*8)*N + n0+tx];
  __syncthreads();
  #pragma unroll
  for(int rr=0;rr<4;rr++)
    out[moff + (size_t)(n0+ty+rr*8)*K + k0+tx] = (__bf16)tile[tx][ty+rr*8];
}

// out_proj K-concat transpose: [layer][dir][1024][512] f32 -> [layer][512][2048] bf16
__global__ __launch_bounds__(256) void transpose_outw_kernel(
    const float* __restrict__ in, __bf16* __restrict__ out)
{
  __shared__ float tile[32][33];
  int z = blockIdx.z, layer = z>>1, dir = z&1;
  int n0 = blockIdx.x*32, k0 = blockIdx.y*32;
  int tx = threadIdx.x, ty = threadIdx.y;
  const float* ip = in + (size_t)z*1024*512;
  #pragma unroll
  for(int rr=0;rr<4;rr++)
    tile[ty+rr*8][tx] = ip[(size_t)(k0+ty+rr*8)*512 + n0+tx];
  __syncthreads();
  __bf16* op = out + (size_t)layer*512*2048 + (size_t)dir*1024;
  #pragma unroll
  for(int rr=0;rr<4;rr++)
    op[(size_t)(n0+ty+rr*8)*2048 + k0+tx] = (__bf16)tile[tx][ty+rr*8];
}

// ---------------------------------------------------------------------------
__global__ __launch_bounds__(256) void bn_patchify_kernel(
    const float* __restrict__ x, const float* __restrict__ bng,
    const float* __restrict__ bnb, const float* __restrict__ bnm,
    const float* __restrict__ bnv, __bf16* __restrict__ Abuf)
{
  int idx = blockIdx.x*256 + threadIdx.x;
  int row = idx / KPAD, k = idx % KPAD;
  int b = row >> 4, l = row & 15;
  float v = 0.f;
  if(k < C_IN*PATCH){
    int c = k / PATCH, j = k % PATCH;
    float xv = x[(b*C_IN + c)*TT + l*PATCH + j];
    v = (xv - bnm[c]) * rsqrtf(bnv[c] + EPS) * bng[c] + bnb[c];
  }
  Abuf[idx] = (__bf16)v;
}

__global__ __launch_bounds__(256) void cast_pad_pw_kernel(
    const float* __restrict__ pw, __bf16* __restrict__ pwb)
{
  int idx = blockIdx.x*256 + threadIdx.x;
  if(idx >= 512*KPAD) return;
  int n = idx / KPAD, k = idx % KPAD;
  pwb[idx] = (__bf16)(k < C_IN*PATCH ? pw[n*(C_IN*PATCH) + k] : 0.f);
}

// ---------------------------------------------------------------------------
// Generic MFMA bf16 GEMM (swapped-operand epilogue: reg axis = 4 consecutive
// features -> vectorized stores). C[M,N](f32) (+)= A[M,K]@Bt[N,K]^T.
// EPI: 0 plain f32 float4 store (ACC = read-modify-write float4);
//      1 dual store f32 float4 + bf16x4;  2 Cb = bf16(softplus(acc+bias[n])).
// Batched over blockIdx.z with element strides sA/sB/sC/sBias.
// ---------------------------------------------------------------------------
template<int BM, int BN, int BK, int ACC, int EPI>
__global__ __launch_bounds__(256) void mfma_gemm(
    const __bf16* __restrict__ A, const __bf16* __restrict__ Bt,
    float* __restrict__ C, __bf16* __restrict__ Cb,
    const float* __restrict__ bias, int N, int K, int lda, int ldb,
    size_t sA, size_t sB, size_t sC, size_t sBias)
{
  constexpr int NGA = BM/16, NGB = BN/16;
  constexpr int APW = NGA/4, BPW = NGB/4;
  constexpr int MI  = BM/32, FN  = BN/32;
  constexpr int NSL = BK/32;
  __shared__ __align__(16) __bf16 As[NSL*NGA*512];
  __shared__ __align__(16) __bf16 Bs[NSL*NGB*512];
  int z = blockIdx.z;
  A  += (size_t)z*sA;  Bt += (size_t)z*sB;
  if(EPI!=2) C += (size_t)z*sC;
  if(EPI!=0) Cb += (size_t)z*sC;
  if(EPI==2) bias += (size_t)z*sBias;
  int tid  = threadIdx.x;
  int lane = tid & 63, w = tid >> 6;
  int wrow = w >> 1, wcol = w & 1;
  int r = lane & 15, q = lane >> 4;
  int row0 = blockIdx.y*BM, col0 = blockIdx.x*BN;

  f32x4 acc[MI][FN];
  #pragma unroll
  for(int i=0;i<MI;i++)
    #pragma unroll
    for(int j=0;j<FN;j++) acc[i][j] = (f32x4)0.f;

  const __bf16* aSrc[APW];
  #pragma unroll
  for(int g=0;g<APW;g++)
    aSrc[g] = A + (size_t)(row0 + (w*APW+g)*16 + r)*lda + q*8;
  const __bf16* bSrc[BPW];
  #pragma unroll
  for(int g=0;g<BPW;g++)
    bSrc[g] = Bt + (size_t)(col0 + (w*BPW+g)*16 + r)*ldb + q*8;

  for(int k0=0;k0<K;k0+=BK){
    #pragma unroll
    for(int s=0;s<NSL;s++){
      #pragma unroll
      for(int g=0;g<APW;g++)
        gload_lds16(aSrc[g] + k0 + s*32, As + (s*NGA + w*APW+g)*512);
      #pragma unroll
      for(int g=0;g<BPW;g++)
        gload_lds16(bSrc[g] + k0 + s*32, Bs + (s*NGB + w*BPW+g)*512);
    }
    __syncthreads();
    #pragma unroll
    for(int s=0;s<NSL;s++){
      bf16x8 aF[MI], bF[FN];
      #pragma unroll
      for(int i=0;i<MI;i++)
        aF[i] = *(const bf16x8*)(As + (s*NGA + wrow*MI+i)*512 + lane*8);
      #pragma unroll
      for(int j=0;j<FN;j++)
        bF[j] = *(const bf16x8*)(Bs + (s*NGB + wcol*FN+j)*512 + lane*8);
      #pragma unroll
      for(int i=0;i<MI;i++)
        #pragma unroll
        for(int j=0;j<FN;j++)
          acc[i][j] = __builtin_amdgcn_mfma_f32_16x16x32_bf16(bF[j], aF[i], acc[i][j], 0, 0, 0);
    }
    __syncthreads();
  }

  // swapped layout: col(lane&15)=row-of-C (token), reg p = consecutive cols
  #pragma unroll
  for(int i=0;i<MI;i++){
    int m = row0 + wrow*(BM/2) + i*16 + r;
    #pragma unroll
    for(int j=0;j<FN;j++){
      int n = col0 + wcol*(BN/2) + j*16 + q*4;
      if(EPI==2){
        const float* bp = bias + n;
        bf16x4 hv;
        #pragma unroll
        for(int p=0;p<4;p++) hv[p] = (__bf16)softplusf(acc[i][j][p] + bp[p]);
        *(bf16x4*)(Cb + (size_t)m*N + n) = hv;
      } else {
        float* cp = C + (size_t)m*N + n;
        f32x4 ov = acc[i][j];
        if(ACC){
          f32x4 cv = *(const f32x4*)cp;
          #pragma unroll
          for(int p=0;p<4;p++) ov[p] += cv[p];
        }
        *(f32x4*)cp = ov;
        if(EPI==1){
          bf16x4 hv;
          #pragma unroll
          for(int p=0;p<4;p++) hv[p] = (__bf16)ov[p];
          *(bf16x4*)(Cb + (size_t)m*N + n) = hv;
        }
      }
    }
  }
}

// ---------------------------------------------------------------------------
// in_proj GEMM, both dirs N-concat (M=4096, N=4096, K=512, BK=64, grid 32x32)
// with fused conv(4)+SiLU epilogue. Swapped operands: lane&15 = token,
// reg p = 4 consecutive features -> conv taps via __shfl_up/down(.,m),
// 8B bf16x4 stores. Outputs token order: ucb (u path), szb (z path),
// each [dir][4096][1024] bf16.
// ---------------------------------------------------------------------------
__global__ __launch_bounds__(256) void mfma_inproj_conv(
    const __bf16* __restrict__ A, const __bf16* __restrict__ Bt,
    const float* __restrict__ cw, const float* __restrict__ cb,
    __bf16* __restrict__ ucb, __bf16* __restrict__ szb)
{
  constexpr int LDA = 512, LDB = 512, K = 512;
  __shared__ __align__(16) __bf16 As[2*8*512];
  __shared__ __align__(16) __bf16 Bs[2*8*512];
  __shared__ float4 s_w4[128];
  __shared__ float  s_b[128];
  int tid  = threadIdx.x;
  int lane = tid & 63, w = tid >> 6;
  int wrow = w >> 1, wcol = w & 1;
  int r = lane & 15, q = lane >> 4;
  int row0 = blockIdx.y*128, col0 = blockIdx.x*128;

  int dirq = col0 >> 11;                  // dir from N-concat
  int feat0 = col0 & 2047;
  bool is_u = feat0 < 1024;               // block-uniform
  int dblk = col0 & 1023;
  const float* cwd = cw + dirq*4096;
  const float* cbd = cb + dirq*1024;
  if(is_u && tid < 128){
    s_w4[tid] = ((const float4*)cwd)[dblk + tid];
    s_b[tid]  = cbd[dblk + tid];
  }

  f32x4 acc[4][4];
  #pragma unroll
  for(int i=0;i<4;i++)
    #pragma unroll
    for(int j=0;j<4;j++) acc[i][j] = (f32x4)0.f;

  const __bf16* aSrc[2];
  #pragma unroll
  for(int g=0;g<2;g++)
    aSrc[g] = A + (size_t)(row0 + (w*2+g)*16 + r)*LDA + q*8;
  const __bf16* bSrc[2];
  #pragma unroll
  for(int g=0;g<2;g++)
    bSrc[g] = Bt + (size_t)(col0 + (w*2+g)*16 + r)*LDB + q*8;

  for(int k0=0;k0<K;k0+=64){
    #pragma unroll
    for(int s=0;s<2;s++){
      #pragma unroll
      for(int g=0;g<2;g++)
        gload_lds16(aSrc[g] + k0 + s*32, As + (s*8 + w*2+g)*512);
      #pragma unroll
      for(int g=0;g<2;g++)
        gload_lds16(bSrc[g] + k0 + s*32, Bs + (s*8 + w*2+g)*512);
    }
    __syncthreads();
    #pragma unroll
    for(int s=0;s<2;s++){
      bf16x8 aF[4], bF[4];
      #pragma unroll
      for(int i=0;i<4;i++)
        aF[i] = *(const bf16x8*)(As + (s*8 + wrow*4+i)*512 + lane*8);
      #pragma unroll
      for(int j=0;j<4;j++)
        bF[j] = *(const bf16x8*)(Bs + (s*8 + wcol*4+j)*512 + lane*8);
      #pragma unroll
      for(int i=0;i<4;i++)
        #pragma unroll
        for(int j=0;j<4;j++)
          acc[i][j] = __builtin_amdgcn_mfma_f32_16x16x32_bf16(bF[j], aF[i], acc[i][j], 0, 0, 0);
    }
    __syncthreads();
  }

  __bf16* ucbD = ucb + (size_t)dirq*NROWS*1024;
  __bf16* szD  = szb + (size_t)dirq*NROWS*1024;

  #pragma unroll
  for(int i=0;i<4;i++){
    int tok = row0 + wrow*64 + i*16 + r;   // token-within-seq t == r
    #pragma unroll
    for(int j=0;j<4;j++){
      int nloc = wcol*64 + j*16 + q*4;     // local feature base (mult of 4)
      if(is_u){
        int f = nloc;                      // feature in [0,128) within block
        int d = dblk + f;
        float vout[4];
        if(dirq==0){
          #pragma unroll
          for(int p=0;p<4;p++){
            float cur = acc[i][j][p];
            float m1 = __shfl_up(cur, 1, 64);
            float m2 = __shfl_up(cur, 2, 64);
            float m3 = __shfl_up(cur, 3, 64);
            float4 w4 = s_w4[f+p];
            float v = s_b[f+p] + w4.w*cur;
            v += (r>=1)? w4.z*m1 : 0.f;
            v += (r>=2)? w4.y*m2 : 0.f;
            v += (r>=3)? w4.x*m3 : 0.f;
            vout[p] = v;
          }
        } else {
          #pragma unroll
          for(int p=0;p<4;p++){
            float cur = acc[i][j][p];
            float p1 = __shfl_down(cur, 1, 64);
            float p2 = __shfl_down(cur, 2, 64);
            float p3 = __shfl_down(cur, 3, 64);
            float4 w4 = s_w4[f+p];
            float v = s_b[f+p] + w4.w*cur;
            v += (r<=14)? w4.z*p1 : 0.f;
            v += (r<=13)? w4.y*p2 : 0.f;
            v += (r<=12)? w4.x*p3 : 0.f;
            vout[p] = v;
          }
        }
        bf16x4 hv;
        #pragma unroll
        for(int p=0;p<4;p++) hv[p] = (__bf16)siluf(vout[p]);
        *(bf16x4*)(ucbD + (size_t)tok*1024 + d) = hv;
      } else {
        int dz = feat0 - 1024 + nloc;
        bf16x4 hv;
        #pragma unroll
        for(int p=0;p<4;p++) hv[p] = (__bf16)siluf(acc[i][j][p]);
        *(bf16x4*)(szD + (size_t)tok*1024 + dz) = hv;
      }
    }
  }
}

// ---------------------------------------------------------------------------
__global__ __launch_bounds__(256) void ln_pos_kernel(
    const float* __restrict__ in, const float* __restrict__ pb,
    const float* __restrict__ g, const float* __restrict__ bt,
    const float* __restrict__ pos, float* __restrict__ out)
{
  __shared__ float sred[4];
  int row = blockIdx.x; int l = row & 15; int tid = threadIdx.x;
  const float* ip = in + (size_t)row*512;
  float v0 = ip[tid] + pb[tid], v1 = ip[tid+256] + pb[tid+256];
  float s = block_reduce_sum(v0+v1, sred);
  float mean = s * (1.f/512.f);
  float d0 = v0-mean, d1 = v1-mean;
  float vs = block_reduce_sum(d0*d0+d1*d1, sred);
  float rstd = rsqrtf(vs*(1.f/512.f) + EPS);
  out[(size_t)row*512+tid]     = d0*rstd*g[tid]     + bt[tid]     + pos[l*512+tid];
  out[(size_t)row*512+tid+256] = d1*rstd*g[tid+256] + bt[tid+256] + pos[l*512+tid+256];
}

__global__ __launch_bounds__(256) void ln_bf16_kernel(
    const float* __restrict__ in, const float* __restrict__ g,
    const float* __restrict__ bt, __bf16* __restrict__ out)
{
  __shared__ float sred[4];
  int row = blockIdx.x; int tid = threadIdx.x;
  const float* ip = in + (size_t)row*512;
  float v0 = ip[tid], v1 = ip[tid+256];
  float s = block_reduce_sum(v0+v1, sred);
  float mean = s * (1.f/512.f);
  float d0 = v0-mean, d1 = v1-mean;
  float vs = block_reduce_sum(d0*d0+d1*d1, sred);
  float rstd = rsqrtf(vs*(1.f/512.f) + EPS);
  out[(size_t)row*512+tid]     = (__bf16)(d0*rstd*g[tid]     + bt[tid]);
  out[(size_t)row*512+tid+256] = (__bf16)(d1*rstd*g[tid+256] + bt[tid+256]);
}

__global__ __launch_bounds__(256) void ln_f32_kernel(
    const float* __restrict__ in, const float* __restrict__ g,
    const float* __restrict__ bt, float* __restrict__ out)
{
  __shared__ float sred[4];
  int row = blockIdx.x; int tid = threadIdx.x;
  const float* ip = in + (size_t)row*512;
  float v0 = ip[tid], v1 = ip[tid+256];
  float s = block_reduce_sum(v0+v1, sred);
  float mean = s * (1.f/512.f);
  float d0 = v0-mean, d1 = v1-mean;
  float vs = block_reduce_sum(d0*d0+d1*d1, sred);
  float rstd = rsqrtf(vs*(1.f/512.f) + EPS);
  out[(size_t)row*512+tid]     = d0*rstd*g[tid]     + bt[tid];
  out[(size_t)row*512+tid+256] = d1*rstd*g[tid+256] + bt[tid+256];
}

// ---------------------------------------------------------------------------
// selective scan, both dirs (gridDim.y=8: dir = y>>2). dt/uc/sz bf16 token
// order; proj f32. gb out: [row][2048] bf16 K-concat for out_proj.
// ---------------------------------------------------------------------------
__global__ __launch_bounds__(256) void scan_kernel(
    const __bf16* __restrict__ dtb, const __bf16* __restrict__ ucb,
    const float* __restrict__ proj, const __bf16* __restrict__ szb,
    const float* __restrict__ A_log, const float* __restrict__ Dskip,
    __bf16* __restrict__ gb)
{
  int b = blockIdx.x;
  int dirq = blockIdx.y >> 2;
  int d = (blockIdx.y & 3)*256 + threadIdx.x;
  const __bf16* dtp = dtb + (size_t)dirq*NROWS*1024;
  const __bf16* ucp = ucb + (size_t)dirq*NROWS*1024;
  const float*  prp = proj + (size_t)dirq*NROWS*64;
  const __bf16* szp = szb  + (size_t)dirq*NROWS*1024;
  const float*  Alp = A_log + (size_t)dirq*1024*16;
  float Dv = Dskip[dirq*1024 + d];
  __shared__ float sB[16][16], sC[16][16];
  {
    int s = threadIdx.x >> 4, n = threadIdx.x & 15;
    int tok = dirq ? 15-s : s;
    sB[s][n] = prp[(size_t)(b*16+tok)*64 + 32 + n];
    sC[s][n] = prp[(size_t)(b*16+tok)*64 + 48 + n];
  }
  __syncthreads();
  float a[16], hst[16];
  #pragma unroll
  for(int n=0;n<16;n++){ a[n] = -__expf(Alp[d*16+n]); hst[n]=0.f; }
  for(int s=0;s<16;s++){
    int tok = dirq ? 15-s : s;
    size_t o = (size_t)(b*16+tok)*1024 + d;
    float dtv = (float)dtp[o];
    float ucv = (float)ucp[o];
    float dtu = dtv*ucv;
    float y = 0.f;
    #pragma unroll
    for(int n=0;n<16;n++){
      hst[n] = __expf(dtv*a[n])*hst[n] + dtu*sB[s][n];
      y += hst[n]*sC[s][n];
    }
    float zs = (float)szp[o];
    gb[(size_t)(b*16+tok)*2048 + dirq*1024 + d] = (__bf16)((y + ucv*Dv) * zs);
  }
}

// ---------------------------------------------------------------------------
extern "C" void kernel_launch(void* const* d_in, const int* in_sizes, int n_in,
                              void* d_out, int out_size, void* d_ws, size_t ws_size,
                              hipStream_t stream) {
  (void)in_sizes; (void)n_in; (void)out_size; (void)ws_size;
  const float* x         = (const float*)d_in[0];
  const float* bn_gamma  = (const float*)d_in[1];
  const float* bn_beta   = (const float*)d_in[2];
  const float* bn_mean   = (const float*)d_in[3];
  const float* bn_var    = (const float*)d_in[4];
  const float* patch_w   = (const float*)d_in[5];
  const float* patch_b   = (const float*)d_in[6];
  const float* ln_pg     = (const float*)d_in[7];
  const float* ln_pb     = (const float*)d_in[8];
  const float* pos       = (const float*)d_in[9];
  const float* blk_ln_g  = (const float*)d_in[10];
  const float* blk_ln_b  = (const float*)d_in[11];
  const float* in_proj_w = (const float*)d_in[12];
  const float* conv_w    = (const float*)d_in[13];
  const float* conv_b    = (const float*)d_in[14];
  const float* x_proj_w  = (const float*)d_in[15];
  const float* dt_proj_w = (const float*)d_in[16];
  const float* dt_proj_b = (const float*)d_in[17];
  const float* A_log     = (const float*)d_in[18];
  const float* Dskip     = (const float*)d_in[19];
  const float* out_proj_w= (const float*)d_in[20];
  const float* fin_g     = (const float*)d_in[21];
  const float* fin_b     = (const float*)d_in[22];

  char* p = (char*)d_ws;
  float*  h    = (float*)p;  p += (size_t)NROWS*512*4;      // 8 MB
  float*  proj2= (float*)p;  p += (size_t)2*NROWS*64*4;     // 2 MB
  __bf16* hnb  = (__bf16*)p; p += (size_t)NROWS*512*2;      // 4 MB
  __bf16* ucb2 = (__bf16*)p; p += (size_t)2*NROWS*1024*2;   // 16 MB
  __bf16* szb2 = (__bf16*)p; p += (size_t)2*NROWS*1024*2;   // 16 MB
  __bf16* dtb2 = (__bf16*)p; p += (size_t)2*NROWS*1024*2;   // 16 MB
  __bf16* gbK  = (__bf16*)p; p += (size_t)NROWS*2048*2;     // 16 MB (also patch f32 scratch)
  __bf16* projb2=(__bf16*)p; p += (size_t)2*NROWS*64*2;     // 1 MB
  __bf16* wtin = (__bf16*)p; p += (size_t)4*2048*512*2;     // 8 MB
  __bf16* wtoutK=(__bf16*)p; p += (size_t)2*512*2048*2;     // 4 MB
  __bf16* wtx  = (__bf16*)p; p += (size_t)4*64*1024*2;      // 0.5 MB
  __bf16* wdtT = (__bf16*)p; p += (size_t)4*1024*32*2;      // 0.25 MB
  __bf16* Abuf = (__bf16*)p; p += (size_t)NROWS*KPAD*2;     // 0.75 MB
  __bf16* pwb  = (__bf16*)p; p += (size_t)512*KPAD*2;       // 96 KB

  // ---- weight prep ----
  transpose_bf16_kernel<<<dim3(64, 16, 4), dim3(32,8), 0, stream>>>(
      in_proj_w, wtin, 512, 2048);
  transpose_outw_kernel<<<dim3(16, 32, 4), dim3(32,8), 0, stream>>>(
      out_proj_w, wtoutK);
  transpose_bf16_kernel<<<dim3(2, 32, 4), dim3(32,8), 0, stream>>>(
      x_proj_w, wtx, 1024, 64);
  transpose_bf16_kernel<<<dim3(32, 1, 4), dim3(32,8), 0, stream>>>(
      dt_proj_w, wdtT, 32, 1024);
  cast_pad_pw_kernel<<<(512*KPAD + 255)/256, 256, 0, stream>>>(patch_w, pwb);

  // ---- patch embed ----
  bn_patchify_kernel<<<(NROWS*KPAD)/256, 256, 0, stream>>>(
      x, bn_gamma, bn_beta, bn_mean, bn_var, Abuf);
  mfma_gemm<128,128,32,0,0><<<dim3(4, 32, 1), 256, 0, stream>>>(
      Abuf, pwb, (float*)gbK, nullptr, nullptr, 512, KPAD, KPAD, KPAD, 0,0,0,0);
  ln_pos_kernel<<<NROWS, 256, 0, stream>>>((float*)gbK, patch_b, ln_pg, ln_pb, pos, h);

  for(int i=0;i<2;i++){
    ln_bf16_kernel<<<NROWS, 256, 0, stream>>>(h, blk_ln_g + i*512, blk_ln_b + i*512, hnb);
    // in_proj both dirs + conv + silu -> ucb2/szb2 (bf16, token order)
    mfma_inproj_conv<<<dim3(32, 32), 256, 0, stream>>>(
        hnb, wtin + (size_t)i*4096*512, conv_w + (size_t)i*2*4096,
        conv_b + (size_t)i*2*1024, ucb2, szb2);
    // x_proj (z=2 dirs): proj f32 + projb bf16
    mfma_gemm<64,64,64,0,1><<<dim3(1, 64, 2), 256, 0, stream>>>(
        ucb2, wtx + (size_t)i*2*64*1024, proj2, projb2, nullptr,
        64, 1024, 1024, 1024,
        (size_t)NROWS*1024, (size_t)64*1024, (size_t)NROWS*64, 0);
    // dt = softplus(dtr @ Wdt + bias) -> bf16
    mfma_gemm<64,64,32,0,2><<<dim3(16, 64, 2), 256, 0, stream>>>(
        projb2, wdtT + (size_t)i*2*1024*32, nullptr, dtb2, dt_proj_b + (size_t)i*2*1024,
        1024, 32, 64, 32,
        (size_t)NROWS*64, (size_t)1024*32, (size_t)NROWS*1024, 1024);
    // scan both dirs -> gbK [row][2048]
    scan_kernel<<<dim3(BB, 8), 256, 0, stream>>>(
        dtb2, ucb2, proj2, szb2, A_log + (size_t)i*2*1024*16,
        Dskip + (size_t)i*2*1024, gbK);
    // out_proj both dirs, K=2048, accumulate into h
    mfma_gemm<64,64,64,1,0><<<dim3(8, 64, 1), 256, 0, stream>>>(
        gbK, wtoutK + (size_t)i*512*2048, h, nullptr, nullptr,
        512, 2048, 2048, 2048, 0,0,0,0);
  }
  ln_f32_kernel<<<NROWS, 256, 0, stream>>>(h, fin_g, fin_b, (float*)d_out);
}

// Round 7
// 495.526 us; speedup vs baseline: 1.4183x; 1.0036x over previous
//
#include <hip/hip_runtime.h>
#include <math.h>
#include <stdint.h>

#define BB 256
#define C_IN 7
#define TT 160
#define PATCH 10
#define D_MODEL 512
#define L_TOK 16
#define D_INNER 1024
#define D_STATE 16
#define DT_RANK 32
#define EPS 1e-5f
#define NROWS (BB*L_TOK)   // 4096
#define KPAD 96            // 70 padded to 3*32

typedef __bf16 bf16x8 __attribute__((ext_vector_type(8)));
typedef __bf16 bf16x4 __attribute__((ext_vector_type(4)));
typedef float  f32x4  __attribute__((ext_vector_type(4)));

__device__ __forceinline__ float siluf(float x){ return x / (1.f + __expf(-x)); }
__device__ __forceinline__ float softplusf(float x){ return (x > 20.f) ? x : log1pf(__expf(x)); }

__device__ __forceinline__ void gload_lds16(const void* gp, void* lp){
  __builtin_amdgcn_global_load_lds(
      (const __attribute__((address_space(1))) unsigned int*)(uintptr_t)gp,
      (__attribute__((address_space(3))) unsigned int*)(uintptr_t)lp, 16, 0, 0);
}

__device__ __forceinline__ float block_reduce_sum(float v, float* sred4){
  for(int off=32; off>0; off>>=1) v += __shfl_down(v, off, 64);
  int lane = threadIdx.x & 63, wid = threadIdx.x >> 6;
  if(lane==0) sred4[wid] = v;
  __syncthreads();
  if(threadIdx.x==0) sred4[0] = sred4[0]+sred4[1]+sred4[2]+sred4[3];
  __syncthreads();
  float r = sred4[0];
  __syncthreads();
  return r;
}

// ---------------------------------------------------------------------------
// transpose + fp32->bf16: in [z][K][N] f32 -> out [z][N][K] bf16
// ---------------------------------------------------------------------------
__global__ __launch_bounds__(256) void transpose_bf16_kernel(
    const float* __restrict__ in, __bf16* __restrict__ out, int K, int N)
{
  __shared__ float tile[32][33];
  size_t moff = (size_t)blockIdx.z * K * N;
  int n0 = blockIdx.x*32, k0 = blockIdx.y*32;
  int tx = threadIdx.x, ty = threadIdx.y;
  #pragma unroll
  for(int rr=0;rr<4;rr++)
    tile[ty+rr*8][tx] = in[moff + (size_t)(k0+ty+rr*8)*N + n0+tx];
  __syncthreads();
  #pragma unroll
  for(int rr=0;rr<4;rr++)
    out[moff + (size_t)(n0+ty+rr*8)*K + k0+tx] = (__bf16)tile[tx][ty+rr*8];
}

// out_proj K-concat transpose: [layer][dir][1024][512] f32 -> [layer][512][2048] bf16
__global__ __launch_bounds__(256) void transpose_outw_kernel(
    const float* __restrict__ in, __bf16* __restrict__ out)
{
  __shared__ float tile[32][33];
  int z = blockIdx.z, layer = z>>1, dir = z&1;
  int n0 = blockIdx.x*32, k0 = blockIdx.y*32;
  int tx = threadIdx.x, ty = threadIdx.y;
  const float* ip = in + (size_t)z*1024*512;
  #pragma unroll
  for(int rr=0;rr<4;rr++)
    tile[ty+rr*8][tx] = ip[(size_t)(k0+ty+rr*8)*512 + n0+tx];
  __syncthreads();
  __bf16* op = out + (size_t)layer*512*2048 + (size_t)dir*1024;
  #pragma unroll
  for(int rr=0;rr<4;rr++)
    op[(size_t)(n0+ty+rr*8)*2048 + k0+tx] = (__bf16)tile[tx][ty+rr*8];
}

// ---------------------------------------------------------------------------
__global__ __launch_bounds__(256) void bn_patchify_kernel(
    const float* __restrict__ x, const float* __restrict__ bng,
    const float* __restrict__ bnb, const float* __restrict__ bnm,
    const float* __restrict__ bnv, __bf16* __restrict__ Abuf)
{
  int idx = blockIdx.x*256 + threadIdx.x;
  int row = idx / KPAD, k = idx % KPAD;
  int b = row >> 4, l = row & 15;
  float v = 0.f;
  if(k < C_IN*PATCH){
    int c = k / PATCH, j = k % PATCH;
    float xv = x[(b*C_IN + c)*TT + l*PATCH + j];
    v = (xv - bnm[c]) * rsqrtf(bnv[c] + EPS) * bng[c] + bnb[c];
  }
  Abuf[idx] = (__bf16)v;
}

__global__ __launch_bounds__(256) void cast_pad_pw_kernel(
    const float* __restrict__ pw, __bf16* __restrict__ pwb)
{
  int idx = blockIdx.x*256 + threadIdx.x;
  if(idx >= 512*KPAD) return;
  int n = idx / KPAD, k = idx % KPAD;
  pwb[idx] = (__bf16)(k < C_IN*PATCH ? pw[n*(C_IN*PATCH) + k] : 0.f);
}

// ---------------------------------------------------------------------------
// Generic MFMA bf16 GEMM (swapped-operand epilogue: reg axis = 4 consecutive
// features -> vectorized stores). C[M,N](f32) (+)= A[M,K]@Bt[N,K]^T.
// EPI: 0 plain f32 float4 store (ACC = read-modify-write float4);
//      1 dual store f32 float4 + bf16x4;  2 Cb = bf16(softplus(acc+bias[n])).
// Batched over blockIdx.z with element strides sA/sB/sC/sBias.
// ---------------------------------------------------------------------------
template<int BM, int BN, int BK, int ACC, int EPI>
__global__ __launch_bounds__(256) void mfma_gemm(
    const __bf16* __restrict__ A, const __bf16* __restrict__ Bt,
    float* __restrict__ C, __bf16* __restrict__ Cb,
    const float* __restrict__ bias, int N, int K, int lda, int ldb,
    size_t sA, size_t sB, size_t sC, size_t sBias)
{
  constexpr int NGA = BM/16, NGB = BN/16;
  constexpr int APW = NGA/4, BPW = NGB/4;
  constexpr int MI  = BM/32, FN  = BN/32;
  constexpr int NSL = BK/32;
  __shared__ __align__(16) __bf16 As[NSL*NGA*512];
  __shared__ __align__(16) __bf16 Bs[NSL*NGB*512];
  int z = blockIdx.z;
  A  += (size_t)z*sA;  Bt += (size_t)z*sB;
  if(EPI!=2) C += (size_t)z*sC;
  if(EPI!=0) Cb += (size_t)z*sC;
  if(EPI==2) bias += (size_t)z*sBias;
  int tid  = threadIdx.x;
  int lane = tid & 63, w = tid >> 6;
  int wrow = w >> 1, wcol = w & 1;
  int r = lane & 15, q = lane >> 4;
  int row0 = blockIdx.y*BM, col0 = blockIdx.x*BN;

  f32x4 acc[MI][FN];
  #pragma unroll
  for(int i=0;i<MI;i++)
    #pragma unroll
    for(int j=0;j<FN;j++) acc[i][j] = (f32x4)0.f;

  const __bf16* aSrc[APW];
  #pragma unroll
  for(int g=0;g<APW;g++)
    aSrc[g] = A + (size_t)(row0 + (w*APW+g)*16 + r)*lda + q*8;
  const __bf16* bSrc[BPW];
  #pragma unroll
  for(int g=0;g<BPW;g++)
    bSrc[g] = Bt + (size_t)(col0 + (w*BPW+g)*16 + r)*ldb + q*8;

  for(int k0=0;k0<K;k0+=BK){
    #pragma unroll
    for(int s=0;s<NSL;s++){
      #pragma unroll
      for(int g=0;g<APW;g++)
        gload_lds16(aSrc[g] + k0 + s*32, As + (s*NGA + w*APW+g)*512);
      #pragma unroll
      for(int g=0;g<BPW;g++)
        gload_lds16(bSrc[g] + k0 + s*32, Bs + (s*NGB + w*BPW+g)*512);
    }
    __syncthreads();
    #pragma unroll
    for(int s=0;s<NSL;s++){
      bf16x8 aF[MI], bF[FN];
      #pragma unroll
      for(int i=0;i<MI;i++)
        aF[i] = *(const bf16x8*)(As + (s*NGA + wrow*MI+i)*512 + lane*8);
      #pragma unroll
      for(int j=0;j<FN;j++)
        bF[j] = *(const bf16x8*)(Bs + (s*NGB + wcol*FN+j)*512 + lane*8);
      #pragma unroll
      for(int i=0;i<MI;i++)
        #pragma unroll
        for(int j=0;j<FN;j++)
          acc[i][j] = __builtin_amdgcn_mfma_f32_16x16x32_bf16(bF[j], aF[i], acc[i][j], 0, 0, 0);
    }
    __syncthreads();
  }

  // swapped layout: col(lane&15)=row-of-C (token), reg p = consecutive cols
  #pragma unroll
  for(int i=0;i<MI;i++){
    int m = row0 + wrow*(BM/2) + i*16 + r;
    #pragma unroll
    for(int j=0;j<FN;j++){
      int n = col0 + wcol*(BN/2) + j*16 + q*4;
      if(EPI==2){
        const float* bp = bias + n;
        bf16x4 hv;
        #pragma unroll
        for(int p=0;p<4;p++) hv[p] = (__bf16)softplusf(acc[i][j][p] + bp[p]);
        *(bf16x4*)(Cb + (size_t)m*N + n) = hv;
      } else {
        float* cp = C + (size_t)m*N + n;
        f32x4 ov = acc[i][j];
        if(ACC){
          f32x4 cv = *(const f32x4*)cp;
          #pragma unroll
          for(int p=0;p<4;p++) ov[p] += cv[p];
        }
        *(f32x4*)cp = ov;
        if(EPI==1){
          bf16x4 hv;
          #pragma unroll
          for(int p=0;p<4;p++) hv[p] = (__bf16)ov[p];
          *(bf16x4*)(Cb + (size_t)m*N + n) = hv;
        }
      }
    }
  }
}

// ---------------------------------------------------------------------------
// in_proj GEMM, both dirs N-concat (M=4096, N=4096, K=512), BM=128, BN=64,
// BK=64, grid 64x32 = 2048 blocks, acc 4x2 frags (32 AGPR) for occupancy.
// Fused conv(4)+SiLU epilogue via lane shuffles (lane&15 = token, reg p = 4
// consecutive features). Outputs token order bf16: ucb (u), szb (z).
// ---------------------------------------------------------------------------
__global__ __launch_bounds__(256, 3) void mfma_inproj_conv(
    const __bf16* __restrict__ A, const __bf16* __restrict__ Bt,
    const float* __restrict__ cw, const float* __restrict__ cb,
    __bf16* __restrict__ ucb, __bf16* __restrict__ szb)
{
  constexpr int LDA = 512, LDB = 512, K = 512;
  __shared__ __align__(16) __bf16 As[2*8*512];    // 16 KB
  __shared__ __align__(16) __bf16 Bs[2*4*512];    // 8 KB
  __shared__ float4 s_w4[64];
  __shared__ float  s_b[64];
  int tid  = threadIdx.x;
  int lane = tid & 63, w = tid >> 6;
  int wrow = w >> 1, wcol = w & 1;
  int r = lane & 15, q = lane >> 4;
  int row0 = blockIdx.y*128, col0 = blockIdx.x*64;

  int dirq = col0 >> 11;                  // dir from N-concat
  int feat0 = col0 & 2047;
  bool is_u = feat0 < 1024;               // block-uniform
  int dblk = col0 & 1023;
  const float* cwd = cw + dirq*4096;
  const float* cbd = cb + dirq*1024;
  if(is_u && tid < 64){
    s_w4[tid] = ((const float4*)cwd)[dblk + tid];
    s_b[tid]  = cbd[dblk + tid];
  }

  f32x4 acc[4][2];
  #pragma unroll
  for(int i=0;i<4;i++)
    #pragma unroll
    for(int j=0;j<2;j++) acc[i][j] = (f32x4)0.f;

  const __bf16* aSrc[2];
  #pragma unroll
  for(int g=0;g<2;g++)
    aSrc[g] = A + (size_t)(row0 + (w*2+g)*16 + r)*LDA + q*8;
  const __bf16* bSrc0 = Bt + (size_t)(col0 + w*16 + r)*LDB + q*8;

  for(int k0=0;k0<K;k0+=64){
    #pragma unroll
    for(int s=0;s<2;s++){
      #pragma unroll
      for(int g=0;g<2;g++)
        gload_lds16(aSrc[g] + k0 + s*32, As + (s*8 + w*2+g)*512);
      gload_lds16(bSrc0 + k0 + s*32, Bs + (s*4 + w)*512);
    }
    __syncthreads();
    #pragma unroll
    for(int s=0;s<2;s++){
      bf16x8 aF[4], bF[2];
      #pragma unroll
      for(int i=0;i<4;i++)
        aF[i] = *(const bf16x8*)(As + (s*8 + wrow*4+i)*512 + lane*8);
      #pragma unroll
      for(int j=0;j<2;j++)
        bF[j] = *(const bf16x8*)(Bs + (s*4 + wcol*2+j)*512 + lane*8);
      #pragma unroll
      for(int i=0;i<4;i++)
        #pragma unroll
        for(int j=0;j<2;j++)
          acc[i][j] = __builtin_amdgcn_mfma_f32_16x16x32_bf16(bF[j], aF[i], acc[i][j], 0, 0, 0);
    }
    __syncthreads();
  }

  __bf16* ucbD = ucb + (size_t)dirq*NROWS*1024;
  __bf16* szD  = szb + (size_t)dirq*NROWS*1024;

  #pragma unroll
  for(int i=0;i<4;i++){
    int tok = row0 + wrow*64 + i*16 + r;   // token-within-seq t == r
    #pragma unroll
    for(int j=0;j<2;j++){
      int nloc = wcol*32 + j*16 + q*4;     // local feature base (mult of 4)
      if(is_u){
        int f = nloc;
        int d = dblk + f;
        float vout[4];
        if(dirq==0){
          #pragma unroll
          for(int p=0;p<4;p++){
            float cur = acc[i][j][p];
            float m1 = __shfl_up(cur, 1, 64);
            float m2 = __shfl_up(cur, 2, 64);
            float m3 = __shfl_up(cur, 3, 64);
            float4 w4 = s_w4[f+p];
            float v = s_b[f+p] + w4.w*cur;
            v += (r>=1)? w4.z*m1 : 0.f;
            v += (r>=2)? w4.y*m2 : 0.f;
            v += (r>=3)? w4.x*m3 : 0.f;
            vout[p] = v;
          }
        } else {
          #pragma unroll
          for(int p=0;p<4;p++){
            float cur = acc[i][j][p];
            float p1 = __shfl_down(cur, 1, 64);
            float p2 = __shfl_down(cur, 2, 64);
            float p3 = __shfl_down(cur, 3, 64);
            float4 w4 = s_w4[f+p];
            float v = s_b[f+p] + w4.w*cur;
            v += (r<=14)? w4.z*p1 : 0.f;
            v += (r<=13)? w4.y*p2 : 0.f;
            v += (r<=12)? w4.x*p3 : 0.f;
            vout[p] = v;
          }
        }
        bf16x4 hv;
        #pragma unroll
        for(int p=0;p<4;p++) hv[p] = (__bf16)siluf(vout[p]);
        *(bf16x4*)(ucbD + (size_t)tok*1024 + d) = hv;
      } else {
        int dz = feat0 - 1024 + nloc;
        bf16x4 hv;
        #pragma unroll
        for(int p=0;p<4;p++) hv[p] = (__bf16)siluf(acc[i][j][p]);
        *(bf16x4*)(szD + (size_t)tok*1024 + dz) = hv;
      }
    }
  }
}

// ---------------------------------------------------------------------------
__global__ __launch_bounds__(256) void ln_pos_kernel(
    const float* __restrict__ in, const float* __restrict__ pb,
    const float* __restrict__ g, const float* __restrict__ bt,
    const float* __restrict__ pos, float* __restrict__ out)
{
  __shared__ float sred[4];
  int row = blockIdx.x; int l = row & 15; int tid = threadIdx.x;
  const float* ip = in + (size_t)row*512;
  float v0 = ip[tid] + pb[tid], v1 = ip[tid+256] + pb[tid+256];
  float s = block_reduce_sum(v0+v1, sred);
  float mean = s * (1.f/512.f);
  float d0 = v0-mean, d1 = v1-mean;
  float vs = block_reduce_sum(d0*d0+d1*d1, sred);
  float rstd = rsqrtf(vs*(1.f/512.f) + EPS);
  out[(size_t)row*512+tid]     = d0*rstd*g[tid]     + bt[tid]     + pos[l*512+tid];
  out[(size_t)row*512+tid+256] = d1*rstd*g[tid+256] + bt[tid+256] + pos[l*512+tid+256];
}

__global__ __launch_bounds__(256) void ln_bf16_kernel(
    const float* __restrict__ in, const float* __restrict__ g,
    const float* __restrict__ bt, __bf16* __restrict__ out)
{
  __shared__ float sred[4];
  int row = blockIdx.x; int tid = threadIdx.x;
  const float* ip = in + (size_t)row*512;
  float v0 = ip[tid], v1 = ip[tid+256];
  float s = block_reduce_sum(v0+v1, sred);
  float mean = s * (1.f/512.f);
  float d0 = v0-mean, d1 = v1-mean;
  float vs = block_reduce_sum(d0*d0+d1*d1, sred);
  float rstd = rsqrtf(vs*(1.f/512.f) + EPS);
  out[(size_t)row*512+tid]     = (__bf16)(d0*rstd*g[tid]     + bt[tid]);
  out[(size_t)row*512+tid+256] = (__bf16)(d1*rstd*g[tid+256] + bt[tid+256]);
}

__global__ __launch_bounds__(256) void ln_f32_kernel(
    const float* __restrict__ in, const float* __restrict__ g,
    const float* __restrict__ bt, float* __restrict__ out)
{
  __shared__ float sred[4];
  int row = blockIdx.x; int tid = threadIdx.x;
  const float* ip = in + (size_t)row*512;
  float v0 = ip[tid], v1 = ip[tid+256];
  float s = block_reduce_sum(v0+v1, sred);
  float mean = s * (1.f/512.f);
  float d0 = v0-mean, d1 = v1-mean;
  float vs = block_reduce_sum(d0*d0+d1*d1, sred);
  float rstd = rsqrtf(vs*(1.f/512.f) + EPS);
  out[(size_t)row*512+tid]     = d0*rstd*g[tid]     + bt[tid];
  out[(size_t)row*512+tid+256] = d1*rstd*g[tid+256] + bt[tid+256];
}

// ---------------------------------------------------------------------------
// selective scan, both dirs (gridDim.y=8: dir = y>>2). dt/uc/sz bf16 token
// order; proj f32. gb out: [row][2048] bf16 K-concat for out_proj.
// ---------------------------------------------------------------------------
__global__ __launch_bounds__(256) void scan_kernel(
    const __bf16* __restrict__ dtb, const __bf16* __restrict__ ucb,
    const float* __restrict__ proj, const __bf16* __restrict__ szb,
    const float* __restrict__ A_log, const float* __restrict__ Dskip,
    __bf16* __restrict__ gb)
{
  int b = blockIdx.x;
  int dirq = blockIdx.y >> 2;
  int d = (blockIdx.y & 3)*256 + threadIdx.x;
  const __bf16* dtp = dtb + (size_t)dirq*NROWS*1024;
  const __bf16* ucp = ucb + (size_t)dirq*NROWS*1024;
  const float*  prp = proj + (size_t)dirq*NROWS*64;
  const __bf16* szp = szb  + (size_t)dirq*NROWS*1024;
  const float*  Alp = A_log + (size_t)dirq*1024*16;
  float Dv = Dskip[dirq*1024 + d];
  __shared__ float sB[16][16], sC[16][16];
  {
    int s = threadIdx.x >> 4, n = threadIdx.x & 15;
    int tok = dirq ? 15-s : s;
    sB[s][n] = prp[(size_t)(b*16+tok)*64 + 32 + n];
    sC[s][n] = prp[(size_t)(b*16+tok)*64 + 48 + n];
  }
  __syncthreads();
  float a[16], hst[16];
  #pragma unroll
  for(int n=0;n<16;n++){ a[n] = -__expf(Alp[d*16+n]); hst[n]=0.f; }
  for(int s=0;s<16;s++){
    int tok = dirq ? 15-s : s;
    size_t o = (size_t)(b*16+tok)*1024 + d;
    float dtv = (float)dtp[o];
    float ucv = (float)ucp[o];
    float dtu = dtv*ucv;
    float y = 0.f;
    #pragma unroll
    for(int n=0;n<16;n++){
      hst[n] = __expf(dtv*a[n])*hst[n] + dtu*sB[s][n];
      y += hst[n]*sC[s][n];
    }
    float zs = (float)szp[o];
    gb[(size_t)(b*16+tok)*2048 + dirq*1024 + d] = (__bf16)((y + ucv*Dv) * zs);
  }
}

// ---------------------------------------------------------------------------
extern "C" void kernel_launch(void* const* d_in, const int* in_sizes, int n_in,
                              void* d_out, int out_size, void* d_ws, size_t ws_size,
                              hipStream_t stream) {
  (void)in_sizes; (void)n_in; (void)out_size; (void)ws_size;
  const float* x         = (const float*)d_in[0];
  const float* bn_gamma  = (const float*)d_in[1];
  const float* bn_beta   = (const float*)d_in[2];
  const float* bn_mean   = (const float*)d_in[3];
  const float* bn_var    = (const float*)d_in[4];
  const float* patch_w   = (const float*)d_in[5];
  const float* patch_b   = (const float*)d_in[6];
  const float* ln_pg     = (const float*)d_in[7];
  const float* ln_pb     = (const float*)d_in[8];
  const float* pos       = (const float*)d_in[9];
  const float* blk_ln_g  = (const float*)d_in[10];
  const float* blk_ln_b  = (const float*)d_in[11];
  const float* in_proj_w = (const float*)d_in[12];
  const float* conv_w    = (const float*)d_in[13];
  const float* conv_b    = (const float*)d_in[14];
  const float* x_proj_w  = (const float*)d_in[15];
  const float* dt_proj_w = (const float*)d_in[16];
  const float* dt_proj_b = (const float*)d_in[17];
  const float* A_log     = (const float*)d_in[18];
  const float* Dskip     = (const float*)d_in[19];
  const float* out_proj_w= (const float*)d_in[20];
  const float* fin_g     = (const float*)d_in[21];
  const float* fin_b     = (const float*)d_in[22];

  char* p = (char*)d_ws;
  float*  h    = (float*)p;  p += (size_t)NROWS*512*4;      // 8 MB
  float*  proj2= (float*)p;  p += (size_t)2*NROWS*64*4;     // 2 MB
  __bf16* hnb  = (__bf16*)p; p += (size_t)NROWS*512*2;      // 4 MB
  __bf16* ucb2 = (__bf16*)p; p += (size_t)2*NROWS*1024*2;   // 16 MB
  __bf16* szb2 = (__bf16*)p; p += (size_t)2*NROWS*1024*2;   // 16 MB
  __bf16* dtb2 = (__bf16*)p; p += (size_t)2*NROWS*1024*2;   // 16 MB
  __bf16* gbK  = (__bf16*)p; p += (size_t)NROWS*2048*2;     // 16 MB (also patch f32 scratch)
  __bf16* projb2=(__bf16*)p; p += (size_t)2*NROWS*64*2;     // 1 MB
  __bf16* wtin = (__bf16*)p; p += (size_t)4*2048*512*2;     // 8 MB
  __bf16* wtoutK=(__bf16*)p; p += (size_t)2*512*2048*2;     // 4 MB
  __bf16* wtx  = (__bf16*)p; p += (size_t)4*64*1024*2;      // 0.5 MB
  __bf16* wdtT = (__bf16*)p; p += (size_t)4*1024*32*2;      // 0.25 MB
  __bf16* Abuf = (__bf16*)p; p += (size_t)NROWS*KPAD*2;     // 0.75 MB
  __bf16* pwb  = (__bf16*)p; p += (size_t)512*KPAD*2;       // 96 KB

  // ---- weight prep ----
  transpose_bf16_kernel<<<dim3(64, 16, 4), dim3(32,8), 0, stream>>>(
      in_proj_w, wtin, 512, 2048);
  transpose_outw_kernel<<<dim3(16, 32, 4), dim3(32,8), 0, stream>>>(
      out_proj_w, wtoutK);
  transpose_bf16_kernel<<<dim3(2, 32, 4), dim3(32,8), 0, stream>>>(
      x_proj_w, wtx, 1024, 64);
  transpose_bf16_kernel<<<dim3(32, 1, 4), dim3(32,8), 0, stream>>>(
      dt_proj_w, wdtT, 32, 1024);
  cast_pad_pw_kernel<<<(512*KPAD + 255)/256, 256, 0, stream>>>(patch_w, pwb);

  // ---- patch embed ----
  bn_patchify_kernel<<<(NROWS*KPAD)/256, 256, 0, stream>>>(
      x, bn_gamma, bn_beta, bn_mean, bn_var, Abuf);
  mfma_gemm<128,128,32,0,0><<<dim3(4, 32, 1), 256, 0, stream>>>(
      Abuf, pwb, (float*)gbK, nullptr, nullptr, 512, KPAD, KPAD, KPAD, 0,0,0,0);
  ln_pos_kernel<<<NROWS, 256, 0, stream>>>((float*)gbK, patch_b, ln_pg, ln_pb, pos, h);

  for(int i=0;i<2;i++){
    ln_bf16_kernel<<<NROWS, 256, 0, stream>>>(h, blk_ln_g + i*512, blk_ln_b + i*512, hnb);
    // in_proj both dirs + conv + silu -> ucb2/szb2 (bf16, token order)
    mfma_inproj_conv<<<dim3(64, 32), 256, 0, stream>>>(
        hnb, wtin + (size_t)i*4096*512, conv_w + (size_t)i*2*4096,
        conv_b + (size_t)i*2*1024, ucb2, szb2);
    // x_proj (z=2 dirs): proj f32 + projb bf16
    mfma_gemm<64,64,64,0,1><<<dim3(1, 64, 2), 256, 0, stream>>>(
        ucb2, wtx + (size_t)i*2*64*1024, proj2, projb2, nullptr,
        64, 1024, 1024, 1024,
        (size_t)NROWS*1024, (size_t)64*1024, (size_t)NROWS*64, 0);
    // dt = softplus(dtr @ Wdt + bias) -> bf16
    mfma_gemm<64,64,32,0,2><<<dim3(16, 64, 2), 256, 0, stream>>>(
        projb2, wdtT + (size_t)i*2*1024*32, nullptr, dtb2, dt_proj_b + (size_t)i*2*1024,
        1024, 32, 64, 32,
        (size_t)NROWS*64, (size_t)1024*32, (size_t)NROWS*1024, 1024);
    // scan both dirs -> gbK [row][2048]
    scan_kernel<<<dim3(BB, 8), 256, 0, stream>>>(
        dtb2, ucb2, proj2, szb2, A_log + (size_t)i*2*1024*16,
        Dskip + (size_t)i*2*1024, gbK);
    // out_proj both dirs, K=2048, accumulate into h
    mfma_gemm<64,64,64,1,0><<<dim3(8, 64, 1), 256, 0, stream>>>(
        gbK, wtoutK + (size_t)i*512*2048, h, nullptr, nullptr,
        512, 2048, 2048, 2048, 0,0,0,0);
  }
  ln_f32_kernel<<<NROWS, 256, 0, stream>>>(h, fin_g, fin_b, (float*)d_out);
}

// Round 8
// 491.952 us; speedup vs baseline: 1.4286x; 1.0073x over previous
//
#include <hip/hip_runtime.h>
#include <math.h>
#include <stdint.h>

#define BB 256
#define C_IN 7
#define TT 160
#define PATCH 10
#define D_MODEL 512
#define L_TOK 16
#define D_INNER 1024
#define D_STATE 16
#define DT_RANK 32
#define EPS 1e-5f
#define NROWS (BB*L_TOK)   // 4096
#define KPAD 96            // 70 padded to 3*32

typedef __bf16 bf16x8 __attribute__((ext_vector_type(8)));
typedef __bf16 bf16x4 __attribute__((ext_vector_type(4)));
typedef float  f32x4  __attribute__((ext_vector_type(4)));

__device__ __forceinline__ float siluf(float x){ return x / (1.f + __expf(-x)); }
__device__ __forceinline__ float softplusf(float x){ return (x > 20.f) ? x : log1pf(__expf(x)); }

__device__ __forceinline__ void gload_lds16(const void* gp, void* lp){
  __builtin_amdgcn_global_load_lds(
      (const __attribute__((address_space(1))) unsigned int*)(uintptr_t)gp,
      (__attribute__((address_space(3))) unsigned int*)(uintptr_t)lp, 16, 0, 0);
}

__device__ __forceinline__ float block_reduce_sum(float v, float* sred4){
  for(int off=32; off>0; off>>=1) v += __shfl_down(v, off, 64);
  int lane = threadIdx.x & 63, wid = threadIdx.x >> 6;
  if(lane==0) sred4[wid] = v;
  __syncthreads();
  if(threadIdx.x==0) sred4[0] = sred4[0]+sred4[1]+sred4[2]+sred4[3];
  __syncthreads();
  float r = sred4[0];
  __syncthreads();
  return r;
}

// ---------------------------------------------------------------------------
// transpose + fp32->bf16: in [z][K][N] f32 -> out [z][N][K] bf16
// ---------------------------------------------------------------------------
__global__ __launch_bounds__(256) void transpose_bf16_kernel(
    const float* __restrict__ in, __bf16* __restrict__ out, int K, int N)
{
  __shared__ float tile[32][33];
  size_t moff = (size_t)blockIdx.z * K * N;
  int n0 = blockIdx.x*32, k0 = blockIdx.y*32;
  int tx = threadIdx.x, ty = threadIdx.y;
  #pragma unroll
  for(int rr=0;rr<4;rr++)
    tile[ty+rr*8][tx] = in[moff + (size_t)(k0+ty+rr*8)*N + n0+tx];
  __syncthreads();
  #pragma unroll
  for(int rr=0;rr<4;rr++)
    out[moff + (size_t)(n0+ty+rr*8)*K + k0+tx] = (__bf16)tile[tx][ty+rr*8];
}

// out_proj K-concat transpose: [layer][dir][1024][512] f32 -> [layer][512][2048] bf16
__global__ __launch_bounds__(256) void transpose_outw_kernel(
    const float* __restrict__ in, __bf16* __restrict__ out)
{
  __shared__ float tile[32][33];
  int z = blockIdx.z, layer = z>>1, dir = z&1;
  int n0 = blockIdx.x*32, k0 = blockIdx.y*32;
  int tx = threadIdx.x, ty = threadIdx.y;
  const float* ip = in + (size_t)z*1024*512;
  #pragma unroll
  for(int rr=0;rr<4;rr++)
    tile[ty+rr*8][tx] = ip[(size_t)(k0+ty+rr*8)*512 + n0+tx];
  __syncthreads();
  __bf16* op = out + (size_t)layer*512*2048 + (size_t)dir*1024;
  #pragma unroll
  for(int rr=0;rr<4;rr++)
    op[(size_t)(n0+ty+rr*8)*2048 + k0+tx] = (__bf16)tile[tx][ty+rr*8];
}

// ---------------------------------------------------------------------------
__global__ __launch_bounds__(256) void bn_patchify_kernel(
    const float* __restrict__ x, const float* __restrict__ bng,
    const float* __restrict__ bnb, const float* __restrict__ bnm,
    const float* __restrict__ bnv, __bf16* __restrict__ Abuf)
{
  int idx = blockIdx.x*256 + threadIdx.x;
  int row = idx / KPAD, k = idx % KPAD;
  int b = row >> 4, l = row & 15;
  float v = 0.f;
  if(k < C_IN*PATCH){
    int c = k / PATCH, j = k % PATCH;
    float xv = x[(b*C_IN + c)*TT + l*PATCH + j];
    v = (xv - bnm[c]) * rsqrtf(bnv[c] + EPS) * bng[c] + bnb[c];
  }
  Abuf[idx] = (__bf16)v;
}

__global__ __launch_bounds__(256) void cast_pad_pw_kernel(
    const float* __restrict__ pw, __bf16* __restrict__ pwb)
{
  int idx = blockIdx.x*256 + threadIdx.x;
  if(idx >= 512*KPAD) return;
  int n = idx / KPAD, k = idx % KPAD;
  pwb[idx] = (__bf16)(k < C_IN*PATCH ? pw[n*(C_IN*PATCH) + k] : 0.f);
}

// ---------------------------------------------------------------------------
// Generic MFMA bf16 GEMM (swapped-operand epilogue: reg axis = 4 consecutive
// features -> vectorized stores). C[M,N](f32) (+)= A[M,K]@Bt[N,K]^T.
// EPI: 0 plain f32 float4 store (ACC = read-modify-write float4);
//      1 dual store f32 float4 + bf16x4;  2 Cb = bf16(softplus(acc+bias[n]));
//      3 bf16x4-only store to Cb.
// Batched over blockIdx.z with element strides sA/sB/sC/sBias.
// ---------------------------------------------------------------------------
template<int BM, int BN, int BK, int ACC, int EPI>
__global__ __launch_bounds__(256) void mfma_gemm(
    const __bf16* __restrict__ A, const __bf16* __restrict__ Bt,
    float* __restrict__ C, __bf16* __restrict__ Cb,
    const float* __restrict__ bias, int N, int K, int lda, int ldb,
    size_t sA, size_t sB, size_t sC, size_t sBias)
{
  constexpr int NGA = BM/16, NGB = BN/16;
  constexpr int APW = NGA/4, BPW = NGB/4;
  constexpr int MI  = BM/32, FN  = BN/32;
  constexpr int NSL = BK/32;
  __shared__ __align__(16) __bf16 As[NSL*NGA*512];
  __shared__ __align__(16) __bf16 Bs[NSL*NGB*512];
  int z = blockIdx.z;
  A  += (size_t)z*sA;  Bt += (size_t)z*sB;
  if(EPI==0 || EPI==1) C  += (size_t)z*sC;
  if(EPI!=0)           Cb += (size_t)z*sC;
  if(EPI==2)           bias += (size_t)z*sBias;
  int tid  = threadIdx.x;
  int lane = tid & 63, w = tid >> 6;
  int wrow = w >> 1, wcol = w & 1;
  int r = lane & 15, q = lane >> 4;
  int row0 = blockIdx.y*BM, col0 = blockIdx.x*BN;

  f32x4 acc[MI][FN];
  #pragma unroll
  for(int i=0;i<MI;i++)
    #pragma unroll
    for(int j=0;j<FN;j++) acc[i][j] = (f32x4)0.f;

  const __bf16* aSrc[APW];
  #pragma unroll
  for(int g=0;g<APW;g++)
    aSrc[g] = A + (size_t)(row0 + (w*APW+g)*16 + r)*lda + q*8;
  const __bf16* bSrc[BPW];
  #pragma unroll
  for(int g=0;g<BPW;g++)
    bSrc[g] = Bt + (size_t)(col0 + (w*BPW+g)*16 + r)*ldb + q*8;

  for(int k0=0;k0<K;k0+=BK){
    #pragma unroll
    for(int s=0;s<NSL;s++){
      #pragma unroll
      for(int g=0;g<APW;g++)
        gload_lds16(aSrc[g] + k0 + s*32, As + (s*NGA + w*APW+g)*512);
      #pragma unroll
      for(int g=0;g<BPW;g++)
        gload_lds16(bSrc[g] + k0 + s*32, Bs + (s*NGB + w*BPW+g)*512);
    }
    __syncthreads();
    #pragma unroll
    for(int s=0;s<NSL;s++){
      bf16x8 aF[MI], bF[FN];
      #pragma unroll
      for(int i=0;i<MI;i++)
        aF[i] = *(const bf16x8*)(As + (s*NGA + wrow*MI+i)*512 + lane*8);
      #pragma unroll
      for(int j=0;j<FN;j++)
        bF[j] = *(const bf16x8*)(Bs + (s*NGB + wcol*FN+j)*512 + lane*8);
      #pragma unroll
      for(int i=0;i<MI;i++)
        #pragma unroll
        for(int j=0;j<FN;j++)
          acc[i][j] = __builtin_amdgcn_mfma_f32_16x16x32_bf16(bF[j], aF[i], acc[i][j], 0, 0, 0);
    }
    __syncthreads();
  }

  // swapped layout: col(lane&15)=row-of-C (token), reg p = consecutive cols
  #pragma unroll
  for(int i=0;i<MI;i++){
    int m = row0 + wrow*(BM/2) + i*16 + r;
    #pragma unroll
    for(int j=0;j<FN;j++){
      int n = col0 + wcol*(BN/2) + j*16 + q*4;
      if(EPI==2){
        const float* bp = bias + n;
        bf16x4 hv;
        #pragma unroll
        for(int p=0;p<4;p++) hv[p] = (__bf16)softplusf(acc[i][j][p] + bp[p]);
        *(bf16x4*)(Cb + (size_t)m*N + n) = hv;
      } else if(EPI==3){
        bf16x4 hv;
        #pragma unroll
        for(int p=0;p<4;p++) hv[p] = (__bf16)acc[i][j][p];
        *(bf16x4*)(Cb + (size_t)m*N + n) = hv;
      } else {
        float* cp = C + (size_t)m*N + n;
        f32x4 ov = acc[i][j];
        if(ACC){
          f32x4 cv = *(const f32x4*)cp;
          #pragma unroll
          for(int p=0;p<4;p++) ov[p] += cv[p];
        }
        *(f32x4*)cp = ov;
        if(EPI==1){
          bf16x4 hv;
          #pragma unroll
          for(int p=0;p<4;p++) hv[p] = (__bf16)ov[p];
          *(bf16x4*)(Cb + (size_t)m*N + n) = hv;
        }
      }
    }
  }
}

// ---------------------------------------------------------------------------
// in_proj GEMM, both dirs N-concat (M=4096, N=4096, K=512), BM=128, BN=64,
// BK=64, grid 64x32 = 2048 blocks. XCD-locality swizzle: hardware assigns
// consecutive linear block ids round-robin to the 8 XCDs; remap so each XCD
// owns a contiguous 8-col-block band -> its B working set (512 KB) stays in
// its private 4 MB L2 instead of streaming all of B from L3.
// Fused conv(4)+SiLU epilogue via lane shuffles (lane&15 = token, reg p = 4
// consecutive features). Outputs token order bf16: ucb (u), szb (z).
// ---------------------------------------------------------------------------
__global__ __launch_bounds__(256, 3) void mfma_inproj_conv(
    const __bf16* __restrict__ A, const __bf16* __restrict__ Bt,
    const float* __restrict__ cw, const float* __restrict__ cb,
    __bf16* __restrict__ ucb, __bf16* __restrict__ szb)
{
  constexpr int LDA = 512, LDB = 512, K = 512;
  __shared__ __align__(16) __bf16 As[2*8*512];    // 16 KB
  __shared__ __align__(16) __bf16 Bs[2*4*512];    // 8 KB
  __shared__ float4 s_w4[64];
  __shared__ float  s_b[64];
  int tid  = threadIdx.x;
  int lane = tid & 63, w = tid >> 6;
  int wrow = w >> 1, wcol = w & 1;
  int r = lane & 15, q = lane >> 4;

  // XCD-band swizzle: lin%8 = XCD (dispatch heuristic); each XCD gets cols
  // [xcd*8, xcd*8+8) x all rows.
  int lin  = blockIdx.x + gridDim.x*blockIdx.y;   // gridDim.x = 64
  int xcd  = lin & 7;
  int idx  = lin >> 3;                            // 0..255
  int colb = xcd*8 + (idx & 7);                   // 0..63
  int rowb = idx >> 3;                            // 0..31
  int row0 = rowb*128, col0 = colb*64;

  int dirq = col0 >> 11;                  // dir from N-concat
  int feat0 = col0 & 2047;
  bool is_u = feat0 < 1024;               // block-uniform
  int dblk = col0 & 1023;
  const float* cwd = cw + dirq*4096;
  const float* cbd = cb + dirq*1024;
  if(is_u && tid < 64){
    s_w4[tid] = ((const float4*)cwd)[dblk + tid];
    s_b[tid]  = cbd[dblk + tid];
  }

  f32x4 acc[4][2];
  #pragma unroll
  for(int i=0;i<4;i++)
    #pragma unroll
    for(int j=0;j<2;j++) acc[i][j] = (f32x4)0.f;

  const __bf16* aSrc[2];
  #pragma unroll
  for(int g=0;g<2;g++)
    aSrc[g] = A + (size_t)(row0 + (w*2+g)*16 + r)*LDA + q*8;
  const __bf16* bSrc0 = Bt + (size_t)(col0 + w*16 + r)*LDB + q*8;

  for(int k0=0;k0<K;k0+=64){
    #pragma unroll
    for(int s=0;s<2;s++){
      #pragma unroll
      for(int g=0;g<2;g++)
        gload_lds16(aSrc[g] + k0 + s*32, As + (s*8 + w*2+g)*512);
      gload_lds16(bSrc0 + k0 + s*32, Bs + (s*4 + w)*512);
    }
    __syncthreads();
    #pragma unroll
    for(int s=0;s<2;s++){
      bf16x8 aF[4], bF[2];
      #pragma unroll
      for(int i=0;i<4;i++)
        aF[i] = *(const bf16x8*)(As + (s*8 + wrow*4+i)*512 + lane*8);
      #pragma unroll
      for(int j=0;j<2;j++)
        bF[j] = *(const bf16x8*)(Bs + (s*4 + wcol*2+j)*512 + lane*8);
      #pragma unroll
      for(int i=0;i<4;i++)
        #pragma unroll
        for(int j=0;j<2;j++)
          acc[i][j] = __builtin_amdgcn_mfma_f32_16x16x32_bf16(bF[j], aF[i], acc[i][j], 0, 0, 0);
    }
    __syncthreads();
  }

  __bf16* ucbD = ucb + (size_t)dirq*NROWS*1024;
  __bf16* szD  = szb + (size_t)dirq*NROWS*1024;

  #pragma unroll
  for(int i=0;i<4;i++){
    int tok = row0 + wrow*64 + i*16 + r;   // token-within-seq t == r
    #pragma unroll
    for(int j=0;j<2;j++){
      int nloc = wcol*32 + j*16 + q*4;     // local feature base (mult of 4)
      if(is_u){
        int f = nloc;
        int d = dblk + f;
        float vout[4];
        if(dirq==0){
          #pragma unroll
          for(int p=0;p<4;p++){
            float cur = acc[i][j][p];
            float m1 = __shfl_up(cur, 1, 64);
            float m2 = __shfl_up(cur, 2, 64);
            float m3 = __shfl_up(cur, 3, 64);
            float4 w4 = s_w4[f+p];
            float v = s_b[f+p] + w4.w*cur;
            v += (r>=1)? w4.z*m1 : 0.f;
            v += (r>=2)? w4.y*m2 : 0.f;
            v += (r>=3)? w4.x*m3 : 0.f;
            vout[p] = v;
          }
        } else {
          #pragma unroll
          for(int p=0;p<4;p++){
            float cur = acc[i][j][p];
            float p1 = __shfl_down(cur, 1, 64);
            float p2 = __shfl_down(cur, 2, 64);
            float p3 = __shfl_down(cur, 3, 64);
            float4 w4 = s_w4[f+p];
            float v = s_b[f+p] + w4.w*cur;
            v += (r<=14)? w4.z*p1 : 0.f;
            v += (r<=13)? w4.y*p2 : 0.f;
            v += (r<=12)? w4.x*p3 : 0.f;
            vout[p] = v;
          }
        }
        bf16x4 hv;
        #pragma unroll
        for(int p=0;p<4;p++) hv[p] = (__bf16)siluf(vout[p]);
        *(bf16x4*)(ucbD + (size_t)tok*1024 + d) = hv;
      } else {
        int dz = feat0 - 1024 + nloc;
        bf16x4 hv;
        #pragma unroll
        for(int p=0;p<4;p++) hv[p] = (__bf16)siluf(acc[i][j][p]);
        *(bf16x4*)(szD + (size_t)tok*1024 + dz) = hv;
      }
    }
  }
}

// ---------------------------------------------------------------------------
__global__ __launch_bounds__(256) void ln_pos_kernel(
    const float* __restrict__ in, const float* __restrict__ pb,
    const float* __restrict__ g, const float* __restrict__ bt,
    const float* __restrict__ pos, float* __restrict__ out)
{
  __shared__ float sred[4];
  int row = blockIdx.x; int l = row & 15; int tid = threadIdx.x;
  const float* ip = in + (size_t)row*512;
  float v0 = ip[tid] + pb[tid], v1 = ip[tid+256] + pb[tid+256];
  float s = block_reduce_sum(v0+v1, sred);
  float mean = s * (1.f/512.f);
  float d0 = v0-mean, d1 = v1-mean;
  float vs = block_reduce_sum(d0*d0+d1*d1, sred);
  float rstd = rsqrtf(vs*(1.f/512.f) + EPS);
  out[(size_t)row*512+tid]     = d0*rstd*g[tid]     + bt[tid]     + pos[l*512+tid];
  out[(size_t)row*512+tid+256] = d1*rstd*g[tid+256] + bt[tid+256] + pos[l*512+tid+256];
}

__global__ __launch_bounds__(256) void ln_bf16_kernel(
    const float* __restrict__ in, const float* __restrict__ g,
    const float* __restrict__ bt, __bf16* __restrict__ out)
{
  __shared__ float sred[4];
  int row = blockIdx.x; int tid = threadIdx.x;
  const float* ip = in + (size_t)row*512;
  float v0 = ip[tid], v1 = ip[tid+256];
  float s = block_reduce_sum(v0+v1, sred);
  float mean = s * (1.f/512.f);
  float d0 = v0-mean, d1 = v1-mean;
  float vs = block_reduce_sum(d0*d0+d1*d1, sred);
  float rstd = rsqrtf(vs*(1.f/512.f) + EPS);
  out[(size_t)row*512+tid]     = (__bf16)(d0*rstd*g[tid]     + bt[tid]);
  out[(size_t)row*512+tid+256] = (__bf16)(d1*rstd*g[tid+256] + bt[tid+256]);
}

__global__ __launch_bounds__(256) void ln_f32_kernel(
    const float* __restrict__ in, const float* __restrict__ g,
    const float* __restrict__ bt, float* __restrict__ out)
{
  __shared__ float sred[4];
  int row = blockIdx.x; int tid = threadIdx.x;
  const float* ip = in + (size_t)row*512;
  float v0 = ip[tid], v1 = ip[tid+256];
  float s = block_reduce_sum(v0+v1, sred);
  float mean = s * (1.f/512.f);
  float d0 = v0-mean, d1 = v1-mean;
  float vs = block_reduce_sum(d0*d0+d1*d1, sred);
  float rstd = rsqrtf(vs*(1.f/512.f) + EPS);
  out[(size_t)row*512+tid]     = d0*rstd*g[tid]     + bt[tid];
  out[(size_t)row*512+tid+256] = d1*rstd*g[tid+256] + bt[tid+256];
}

// ---------------------------------------------------------------------------
// selective scan, both dirs (gridDim.y=8: dir = y>>2). dt/uc/sz/proj bf16,
// token order. gb out: [row][2048] bf16 K-concat for out_proj.
// ---------------------------------------------------------------------------
__global__ __launch_bounds__(256) void scan_kernel(
    const __bf16* __restrict__ dtb, const __bf16* __restrict__ ucb,
    const __bf16* __restrict__ projb, const __bf16* __restrict__ szb,
    const float* __restrict__ A_log, const float* __restrict__ Dskip,
    __bf16* __restrict__ gb)
{
  int b = blockIdx.x;
  int dirq = blockIdx.y >> 2;
  int d = (blockIdx.y & 3)*256 + threadIdx.x;
  const __bf16* dtp = dtb + (size_t)dirq*NROWS*1024;
  const __bf16* ucp = ucb + (size_t)dirq*NROWS*1024;
  const __bf16* prp = projb + (size_t)dirq*NROWS*64;
  const __bf16* szp = szb  + (size_t)dirq*NROWS*1024;
  const float*  Alp = A_log + (size_t)dirq*1024*16;
  float Dv = Dskip[dirq*1024 + d];
  __shared__ float sB[16][16], sC[16][16];
  {
    int s = threadIdx.x >> 4, n = threadIdx.x & 15;
    int tok = dirq ? 15-s : s;
    sB[s][n] = (float)prp[(size_t)(b*16+tok)*64 + 32 + n];
    sC[s][n] = (float)prp[(size_t)(b*16+tok)*64 + 48 + n];
  }
  __syncthreads();
  float a[16], hst[16];
  #pragma unroll
  for(int n=0;n<16;n++){ a[n] = -__expf(Alp[d*16+n]); hst[n]=0.f; }
  for(int s=0;s<16;s++){
    int tok = dirq ? 15-s : s;
    size_t o = (size_t)(b*16+tok)*1024 + d;
    float dtv = (float)dtp[o];
    float ucv = (float)ucp[o];
    float dtu = dtv*ucv;
    float y = 0.f;
    #pragma unroll
    for(int n=0;n<16;n++){
      hst[n] = __expf(dtv*a[n])*hst[n] + dtu*sB[s][n];
      y += hst[n]*sC[s][n];
    }
    float zs = (float)szp[o];
    gb[(size_t)(b*16+tok)*2048 + dirq*1024 + d] = (__bf16)((y + ucv*Dv) * zs);
  }
}

// ---------------------------------------------------------------------------
extern "C" void kernel_launch(void* const* d_in, const int* in_sizes, int n_in,
                              void* d_out, int out_size, void* d_ws, size_t ws_size,
                              hipStream_t stream) {
  (void)in_sizes; (void)n_in; (void)out_size; (void)ws_size;
  const float* x         = (const float*)d_in[0];
  const float* bn_gamma  = (const float*)d_in[1];
  const float* bn_beta   = (const float*)d_in[2];
  const float* bn_mean   = (const float*)d_in[3];
  const float* bn_var    = (const float*)d_in[4];
  const float* patch_w   = (const float*)d_in[5];
  const float* patch_b   = (const float*)d_in[6];
  const float* ln_pg     = (const float*)d_in[7];
  const float* ln_pb     = (const float*)d_in[8];
  const float* pos       = (const float*)d_in[9];
  const float* blk_ln_g  = (const float*)d_in[10];
  const float* blk_ln_b  = (const float*)d_in[11];
  const float* in_proj_w = (const float*)d_in[12];
  const float* conv_w    = (const float*)d_in[13];
  const float* conv_b    = (const float*)d_in[14];
  const float* x_proj_w  = (const float*)d_in[15];
  const float* dt_proj_w = (const float*)d_in[16];
  const float* dt_proj_b = (const float*)d_in[17];
  const float* A_log     = (const float*)d_in[18];
  const float* Dskip     = (const float*)d_in[19];
  const float* out_proj_w= (const float*)d_in[20];
  const float* fin_g     = (const float*)d_in[21];
  const float* fin_b     = (const float*)d_in[22];

  char* p = (char*)d_ws;
  float*  h    = (float*)p;  p += (size_t)NROWS*512*4;      // 8 MB
  __bf16* hnb  = (__bf16*)p; p += (size_t)NROWS*512*2;      // 4 MB
  __bf16* ucb2 = (__bf16*)p; p += (size_t)2*NROWS*1024*2;   // 16 MB
  __bf16* szb2 = (__bf16*)p; p += (size_t)2*NROWS*1024*2;   // 16 MB
  __bf16* dtb2 = (__bf16*)p; p += (size_t)2*NROWS*1024*2;   // 16 MB
  __bf16* gbK  = (__bf16*)p; p += (size_t)NROWS*2048*2;     // 16 MB (also patch f32 scratch)
  __bf16* projb2=(__bf16*)p; p += (size_t)2*NROWS*64*2;     // 1 MB
  __bf16* wtin = (__bf16*)p; p += (size_t)4*2048*512*2;     // 8 MB
  __bf16* wtoutK=(__bf16*)p; p += (size_t)2*512*2048*2;     // 4 MB
  __bf16* wtx  = (__bf16*)p; p += (size_t)4*64*1024*2;      // 0.5 MB
  __bf16* wdtT = (__bf16*)p; p += (size_t)4*1024*32*2;      // 0.25 MB
  __bf16* Abuf = (__bf16*)p; p += (size_t)NROWS*KPAD*2;     // 0.75 MB
  __bf16* pwb  = (__bf16*)p; p += (size_t)512*KPAD*2;       // 96 KB

  // ---- weight prep ----
  transpose_bf16_kernel<<<dim3(64, 16, 4), dim3(32,8), 0, stream>>>(
      in_proj_w, wtin, 512, 2048);
  transpose_outw_kernel<<<dim3(16, 32, 4), dim3(32,8), 0, stream>>>(
      out_proj_w, wtoutK);
  transpose_bf16_kernel<<<dim3(2, 32, 4), dim3(32,8), 0, stream>>>(
      x_proj_w, wtx, 1024, 64);
  transpose_bf16_kernel<<<dim3(32, 1, 4), dim3(32,8), 0, stream>>>(
      dt_proj_w, wdtT, 32, 1024);
  cast_pad_pw_kernel<<<(512*KPAD + 255)/256, 256, 0, stream>>>(patch_w, pwb);

  // ---- patch embed ----
  bn_patchify_kernel<<<(NROWS*KPAD)/256, 256, 0, stream>>>(
      x, bn_gamma, bn_beta, bn_mean, bn_var, Abuf);
  mfma_gemm<128,128,32,0,0><<<dim3(4, 32, 1), 256, 0, stream>>>(
      Abuf, pwb, (float*)gbK, nullptr, nullptr, 512, KPAD, KPAD, KPAD, 0,0,0,0);
  ln_pos_kernel<<<NROWS, 256, 0, stream>>>((float*)gbK, patch_b, ln_pg, ln_pb, pos, h);

  for(int i=0;i<2;i++){
    ln_bf16_kernel<<<NROWS, 256, 0, stream>>>(h, blk_ln_g + i*512, blk_ln_b + i*512, hnb);
    // in_proj both dirs + conv + silu -> ucb2/szb2 (bf16, token order)
    mfma_inproj_conv<<<dim3(64, 32), 256, 0, stream>>>(
        hnb, wtin + (size_t)i*4096*512, conv_w + (size_t)i*2*4096,
        conv_b + (size_t)i*2*1024, ucb2, szb2);
    // x_proj (z=2 dirs): projb bf16 only
    mfma_gemm<64,64,64,0,3><<<dim3(1, 64, 2), 256, 0, stream>>>(
        ucb2, wtx + (size_t)i*2*64*1024, nullptr, projb2, nullptr,
        64, 1024, 1024, 1024,
        (size_t)NROWS*1024, (size_t)64*1024, (size_t)NROWS*64, 0);
    // dt = softplus(dtr @ Wdt + bias) -> bf16
    mfma_gemm<64,64,32,0,2><<<dim3(16, 64, 2), 256, 0, stream>>>(
        projb2, wdtT + (size_t)i*2*1024*32, nullptr, dtb2, dt_proj_b + (size_t)i*2*1024,
        1024, 32, 64, 32,
        (size_t)NROWS*64, (size_t)1024*32, (size_t)NROWS*1024, 1024);
    // scan both dirs -> gbK [row][2048]
    scan_kernel<<<dim3(BB, 8), 256, 0, stream>>>(
        dtb2, ucb2, projb2, szb2, A_log + (size_t)i*2*1024*16,
        Dskip + (size_t)i*2*1024, gbK);
    // out_proj both dirs, K=2048, accumulate into h
    mfma_gemm<64,64,64,1,0><<<dim3(8, 64, 1), 256, 0, stream>>>(
        gbK, wtoutK + (size_t)i*512*2048, h, nullptr, nullptr,
        512, 2048, 2048, 2048, 0,0,0,0);
  }
  ln_f32_kernel<<<NROWS, 256, 0, stream>>>(h, fin_g, fin_b, (float*)d_out);
}